// Round 16
// baseline (361.595 us; speedup 1.0000x reference)
//
#include <hip/hip_runtime.h>
#include <hip/hip_bf16.h>

typedef __hip_bfloat16 bf16;
typedef __attribute__((ext_vector_type(8))) __bf16 bf16x8;
typedef __attribute__((ext_vector_type(4))) float f32x4;

#define SEQ 2048
#define HID 4096
#define NH 32
#define NKV 8
#define HD 128
#define KVDIM 1024
#define QKVN 6144

#define MiB (1024 * 1024)
// (1/sqrt(128)) * log2(e): folded into rope-Q so attention softmax runs in exp2 domain
#define SCALE_LOG2E 0.12751743f

__device__ __forceinline__ void gl_lds16(const void* g, void* lds) {
  __builtin_amdgcn_global_load_lds((const __attribute__((address_space(1))) void*)g,
                                   (__attribute__((address_space(3))) void*)lds,
                                   16, 0, 0);
}

__device__ __forceinline__ float unplo(unsigned u) { return __uint_as_float(u << 16); }
__device__ __forceinline__ float unphi(unsigned u) { return __uint_as_float(u & 0xffff0000u); }
__device__ __forceinline__ unsigned packbf(float a, float b) {
  bf16 t[2] = {__float2bfloat16(a), __float2bfloat16(b)};
  return *reinterpret_cast<unsigned*>(t);
}

// ---------------- bias concat [4096|1024|1024] ----------------
__global__ void concat_bias_kernel(const float* __restrict__ bq, const float* __restrict__ bk,
                                   const float* __restrict__ bv, float* __restrict__ o) {
  int i = blockIdx.x * blockDim.x + threadIdx.x;
  if (i >= QKVN) return;
  o[i] = (i < HID) ? bq[i] : (i < HID + KVDIM ? bk[i - HID] : bv[i - HID - KVDIM]);
}

// ---------------- merged weight transpose + hidden cvt ----------------
__global__ void transpose_all_kernel(const float* __restrict__ Wq, const float* __restrict__ Wk,
                                     const float* __restrict__ Wv, const float* __restrict__ Wo,
                                     bf16* __restrict__ Wqkvt, bf16* __restrict__ Wot,
                                     const float* __restrict__ hidden, bf16* __restrict__ Xb) {
  __shared__ float tile[32][33];
  int t = blockIdx.x;
  if (t >= 40960) {
    int i = ((t - 40960) * 256 + threadIdx.y * 32 + threadIdx.x) * 4;
    float4 v = *reinterpret_cast<const float4*>(hidden + i);
    bf16 o[4] = {__float2bfloat16(v.x), __float2bfloat16(v.y),
                 __float2bfloat16(v.z), __float2bfloat16(v.w)};
    *reinterpret_cast<short4*>(Xb + i) = *reinterpret_cast<const short4*>(o);
    return;
  }
  const float* in;
  bf16* out;
  int si, xt, yt;
  if (t < 16384)      { in = Wq; out = Wqkvt;                           si = HID;   xt = t & 127; yt = t >> 7; }
  else if (t < 20480) { t -= 16384; in = Wk; out = Wqkvt + (size_t)HID * HID;           si = KVDIM; xt = t & 31; yt = t >> 5; }
  else if (t < 24576) { t -= 20480; in = Wv; out = Wqkvt + (size_t)(HID + KVDIM) * HID; si = KVDIM; xt = t & 31; yt = t >> 5; }
  else                { t -= 24576; in = Wo; out = Wot;                 si = HID;   xt = t & 127; yt = t >> 7; }
  int c0 = xt * 32, r0 = yt * 32;
  int tx = threadIdx.x, ty = threadIdx.y;
#pragma unroll
  for (int i = 0; i < 32; i += 8)
    tile[ty + i][tx] = in[(size_t)(r0 + ty + i) * si + (c0 + tx)];
  __syncthreads();
#pragma unroll
  for (int i = 0; i < 32; i += 8)
    out[(size_t)(c0 + ty + i) * HID + (r0 + tx)] = __float2bfloat16(tile[tx][ty + i]);
}

// ---------------- fused post-QKV: rope Q (pre-scaled), rope K, V transpose ----------------
__global__ void postqkv_kernel(const bf16* __restrict__ Ch, bf16* __restrict__ Qb,
                               bf16* __restrict__ Kb, bf16* __restrict__ Vt) {
  __shared__ float tile[32][33];
  int b = blockIdx.x;
  int tid = threadIdx.x;
  if (b < 10240) {
    bool isQ = (b < 8192);
    int idx = (isQ ? b : b - 8192) * 256 + tid;
    int j = idx & 31;
    int h = (idx >> 5) & (isQ ? 31 : 7);
    int s = idx >> (isQ ? 10 : 8);
    size_t bi = (size_t)s * QKVN + (isQ ? 0 : HID) + h * HD;
    unsigned u1 = *reinterpret_cast<const unsigned*>(Ch + bi + 2 * j);
    unsigned u2 = *reinterpret_cast<const unsigned*>(Ch + bi + 64 + 2 * j);
    float x1a = unplo(u1), x1b = unphi(u1);
    float x2a = unplo(u2), x2b = unphi(u2);
    float inv0 = __expf(-(float)(2 * j) * 0.14391156831212787f);
    float inv1 = __expf(-(float)(2 * j + 1) * 0.14391156831212787f);
    float sn0, cs0, sn1, cs1;
    __sincosf((float)s * inv0, &sn0, &cs0);
    __sincosf((float)s * inv1, &sn1, &cs1);
    if (isQ) {
      cs0 *= SCALE_LOG2E; sn0 *= SCALE_LOG2E;
      cs1 *= SCALE_LOG2E; sn1 *= SCALE_LOG2E;
    }
    size_t bo = (size_t)s * (isQ ? HID : KVDIM) + h * HD;
    bf16* Ob = isQ ? Qb : Kb;
    *reinterpret_cast<unsigned*>(Ob + bo + 2 * j) =
        packbf(x1a * cs0 - x2a * sn0, x1b * cs1 - x2b * sn1);
    *reinterpret_cast<unsigned*>(Ob + bo + 64 + 2 * j) =
        packbf(x2a * cs0 + x1a * sn0, x2b * cs1 + x1b * sn1);
  } else {
    int t = b - 10240;
    int xt = t & 31, yt = t >> 5;
    int tx = tid & 31, ty = tid >> 5;
#pragma unroll
    for (int i = 0; i < 32; i += 8)
      tile[ty + i][tx] = __bfloat162float(Ch[(size_t)(yt * 32 + ty + i) * QKVN + (HID + KVDIM) + xt * 32 + tx]);
    __syncthreads();
#pragma unroll
    for (int i = 0; i < 32; i += 8)
      Vt[(size_t)(xt * 32 + ty + i) * SEQ + (yt * 32 + tx)] = __float2bfloat16(tile[tx][ty + i]);
  }
}

#define BARRIER() __builtin_amdgcn_s_barrier()
#define LGKM0()                                          \
  {                                                      \
    asm volatile("s_waitcnt lgkmcnt(0)" ::: "memory");   \
    __builtin_amdgcn_sched_barrier(0);                   \
  }
#define MFMA_ACC(d, x, y) d = __builtin_amdgcn_mfma_f32_16x16x32_bf16(x, y, d, 0, 0, 0)

// ---------------- QKV GEMM: 128x192 tile, full K, 512 blocks (2/CU), 2-phase ----------------
// 8 waves = 2M x 4N (per-wave 64x48, acc[4][3]). LDS {A 128x64 | B 192x64} x 2buf = 80 KB.
__global__ __launch_bounds__(512, 4) void qkvgemm_kernel(
    const bf16* __restrict__ A,   // [SEQ][HID]
    const bf16* __restrict__ Bt,  // [QKVN][HID]
    const float* __restrict__ bias,
    bf16* __restrict__ Ch) {      // [SEQ][QKVN]
  __shared__ bf16 lds[2][320 * 64];  // A rows [0,128), B rows [128,320)
  const int blk = blockIdx.x;
  const int sw = (blk & 7) * 64 + (blk >> 3);   // bijective XCD swizzle (512 = 8*64)
  const int bx = sw & 31, by = sw >> 5;          // N32 x M16
  const int n0 = bx * 192;
  const int m0 = by * 128;
  const int tid = threadIdx.x;
  const int lane = tid & 63;
  const int w = tid >> 6;
  const int wr = w >> 2, wc = w & 3;            // 2M x 4N
  const int hig = lane >> 4;
  const int nt = HID / 64;                       // 64

#define QSTAGE_A(buf, t)                                                          \
  {                                                                               \
    _Pragma("unroll")                                                             \
    for (int _c = 0; _c < 2; ++_c) {                                              \
      int _row = _c * 64 + w * 8 + (lane >> 3);                                   \
      int _ch = (lane & 7) ^ ((lane >> 3) & 7);                                   \
      gl_lds16(A + (size_t)(m0 + _row) * HID + (size_t)(t) * 64 + _ch * 8,        \
               &lds[buf][(_c * 64 + w * 8) * 64]);                                \
    }                                                                             \
  }
#define QSTAGE_B(buf, t)                                                          \
  {                                                                               \
    _Pragma("unroll")                                                             \
    for (int _c = 0; _c < 3; ++_c) {                                              \
      int _row = _c * 64 + w * 8 + (lane >> 3);                                   \
      int _ch = (lane & 7) ^ ((lane >> 3) & 7);                                   \
      gl_lds16(Bt + (size_t)(n0 + _row) * HID + (size_t)(t) * 64 + _ch * 8,       \
               &lds[buf][(128 + _c * 64 + w * 8) * 64]);                          \
    }                                                                             \
  }

  auto rdA = [&](int cur, int mi, int ks) {
    int rr = wr * 64 + mi * 16 + (lane & 15);
    int byt = rr * 128 + (((ks * 32 + hig * 8) * 2) ^ ((rr & 7) << 4));
    return *reinterpret_cast<const bf16x8*>(
        reinterpret_cast<const char*>(&lds[cur][0]) + byt);
  };
  auto rdB = [&](int cur, int ni, int ks) {
    int rr = wc * 48 + ni * 16 + (lane & 15);
    int byt = 16384 + rr * 128 + (((ks * 32 + hig * 8) * 2) ^ ((rr & 7) << 4));
    return *reinterpret_cast<const bf16x8*>(
        reinterpret_cast<const char*>(&lds[cur][0]) + byt);
  };

  f32x4 acc[4][3];
  const f32x4 z = {0.f, 0.f, 0.f, 0.f};
#pragma unroll
  for (int i = 0; i < 4; ++i)
#pragma unroll
    for (int j = 0; j < 3; ++j) acc[i][j] = z;

  QSTAGE_A(0, 0); QSTAGE_B(0, 0);   // 5 loads
  QSTAGE_B(1, 1);                    // +3
  asm volatile("s_waitcnt vmcnt(3)" ::: "memory");  // tile0's 5 landed
  BARRIER();

  bf16x8 a[2][2], b[3][2];
  int cur = 0;
  for (int t = 0; t < nt; ++t, cur ^= 1) {
    // ---- P1: rd a0-1 + b0-2; stage A(t+1)->nxt; MFMA upper-M half
#pragma unroll
    for (int mi = 0; mi < 2; ++mi) { a[mi][0] = rdA(cur, mi, 0); a[mi][1] = rdA(cur, mi, 1); }
#pragma unroll
    for (int ni = 0; ni < 3; ++ni) { b[ni][0] = rdB(cur, ni, 0); b[ni][1] = rdB(cur, ni, 1); }
    if (t + 1 < nt) QSTAGE_A(cur ^ 1, t + 1);
    LGKM0();
    __builtin_amdgcn_s_setprio(1);
#pragma unroll
    for (int mi = 0; mi < 2; ++mi)
#pragma unroll
      for (int ni = 0; ni < 3; ++ni) {
        MFMA_ACC(acc[mi][ni], a[mi][0], b[ni][0]);
        MFMA_ACC(acc[mi][ni], a[mi][1], b[ni][1]);
      }
    __builtin_amdgcn_s_setprio(0);
    BARRIER();  // B(cur) reads done -> safe to overwrite
    // ---- P2: rd a2-3; stage B(t+2)->cur; MFMA lower-M half; wait A(t+1)
#pragma unroll
    for (int mi = 0; mi < 2; ++mi) { a[mi][0] = rdA(cur, mi + 2, 0); a[mi][1] = rdA(cur, mi + 2, 1); }
    if (t + 2 < nt) QSTAGE_B(cur, t + 2);
    LGKM0();
    __builtin_amdgcn_s_setprio(1);
#pragma unroll
    for (int mi = 0; mi < 2; ++mi)
#pragma unroll
      for (int ni = 0; ni < 3; ++ni) {
        MFMA_ACC(acc[mi + 2][ni], a[mi][0], b[ni][0]);
        MFMA_ACC(acc[mi + 2][ni], a[mi][1], b[ni][1]);
      }
    __builtin_amdgcn_s_setprio(0);
    if (t + 1 < nt) {
      if (t + 2 < nt) {
        asm volatile("s_waitcnt vmcnt(3)" ::: "memory");  // A(t+1) landed; B(t+2) in flight
      } else {
        asm volatile("s_waitcnt vmcnt(0)" ::: "memory");
      }
    }
    BARRIER();
  }

#pragma unroll
  for (int ni = 0; ni < 3; ++ni) {
    int col = n0 + wc * 48 + ni * 16 + (lane & 15);
    float bv = bias[col];
#pragma unroll
    for (int mi = 0; mi < 4; ++mi) {
      int rbase = m0 + wr * 64 + mi * 16 + hig * 4;
#pragma unroll
      for (int r = 0; r < 4; ++r)
        Ch[(size_t)(rbase + r) * QKVN + col] = __float2bfloat16(acc[mi][ni][r] + bv);
    }
  }
#undef QSTAGE_A
#undef QSTAGE_B
}

// ---------------- Wo GEMM: 128x128 tile, full K, 512 blocks (2/CU), 2-phase ----------------
// 8 waves = 2M x 4N (per-wave 64x32, acc[4][2]). LDS {A 128x64 | B 128x64} x 2buf = 64 KB.
__global__ __launch_bounds__(512, 4) void wogemm_kernel(
    const bf16* __restrict__ A,   // [SEQ][HID]
    const bf16* __restrict__ Bt,  // [HID][HID]
    float* __restrict__ C) {      // [SEQ][HID]
  __shared__ bf16 lds[2][256 * 64];  // A rows [0,128), B rows [128,256)
  const int blk = blockIdx.x;
  const int sw = (blk & 7) * 64 + (blk >> 3);   // bijective XCD swizzle (512 = 8*64)
  const int bx = sw & 31, by = sw >> 5;          // N32 x M16
  const int n0 = bx * 128;
  const int m0 = by * 128;
  const int tid = threadIdx.x;
  const int lane = tid & 63;
  const int w = tid >> 6;
  const int wr = w >> 2, wc = w & 3;
  const int hig = lane >> 4;
  const int nt = HID / 64;

#define WSTAGE_A(buf, t)                                                          \
  {                                                                               \
    _Pragma("unroll")                                                             \
    for (int _c = 0; _c < 2; ++_c) {                                              \
      int _row = _c * 64 + w * 8 + (lane >> 3);                                   \
      int _ch = (lane & 7) ^ ((lane >> 3) & 7);                                   \
      gl_lds16(A + (size_t)(m0 + _row) * HID + (size_t)(t) * 64 + _ch * 8,        \
               &lds[buf][(_c * 64 + w * 8) * 64]);                                \
    }                                                                             \
  }
#define WSTAGE_B(buf, t)                                                          \
  {                                                                               \
    _Pragma("unroll")                                                             \
    for (int _c = 0; _c < 2; ++_c) {                                              \
      int _row = _c * 64 + w * 8 + (lane >> 3);                                   \
      int _ch = (lane & 7) ^ ((lane >> 3) & 7);                                   \
      gl_lds16(Bt + (size_t)(n0 + _row) * HID + (size_t)(t) * 64 + _ch * 8,       \
               &lds[buf][(128 + _c * 64 + w * 8) * 64]);                          \
    }                                                                             \
  }

  auto rdA = [&](int cur, int mi, int ks) {
    int rr = wr * 64 + mi * 16 + (lane & 15);
    int byt = rr * 128 + (((ks * 32 + hig * 8) * 2) ^ ((rr & 7) << 4));
    return *reinterpret_cast<const bf16x8*>(
        reinterpret_cast<const char*>(&lds[cur][0]) + byt);
  };
  auto rdB = [&](int cur, int ni, int ks) {
    int rr = wc * 32 + ni * 16 + (lane & 15);
    int byt = 16384 + rr * 128 + (((ks * 32 + hig * 8) * 2) ^ ((rr & 7) << 4));
    return *reinterpret_cast<const bf16x8*>(
        reinterpret_cast<const char*>(&lds[cur][0]) + byt);
  };

  f32x4 acc[4][2];
  const f32x4 z = {0.f, 0.f, 0.f, 0.f};
#pragma unroll
  for (int i = 0; i < 4; ++i)
#pragma unroll
    for (int j = 0; j < 2; ++j) acc[i][j] = z;

  WSTAGE_A(0, 0); WSTAGE_B(0, 0);   // 4 loads
  WSTAGE_B(1, 1);                    // +2
  asm volatile("s_waitcnt vmcnt(2)" ::: "memory");
  BARRIER();

  bf16x8 a[2][2], b[2][2];
  int cur = 0;
  for (int t = 0; t < nt; ++t, cur ^= 1) {
#pragma unroll
    for (int mi = 0; mi < 2; ++mi) { a[mi][0] = rdA(cur, mi, 0); a[mi][1] = rdA(cur, mi, 1); }
#pragma unroll
    for (int ni = 0; ni < 2; ++ni) { b[ni][0] = rdB(cur, ni, 0); b[ni][1] = rdB(cur, ni, 1); }
    if (t + 1 < nt) WSTAGE_A(cur ^ 1, t + 1);
    LGKM0();
    __builtin_amdgcn_s_setprio(1);
#pragma unroll
    for (int mi = 0; mi < 2; ++mi)
#pragma unroll
      for (int ni = 0; ni < 2; ++ni) {
        MFMA_ACC(acc[mi][ni], a[mi][0], b[ni][0]);
        MFMA_ACC(acc[mi][ni], a[mi][1], b[ni][1]);
      }
    __builtin_amdgcn_s_setprio(0);
    BARRIER();
#pragma unroll
    for (int mi = 0; mi < 2; ++mi) { a[mi][0] = rdA(cur, mi + 2, 0); a[mi][1] = rdA(cur, mi + 2, 1); }
    if (t + 2 < nt) WSTAGE_B(cur, t + 2);
    LGKM0();
    __builtin_amdgcn_s_setprio(1);
#pragma unroll
    for (int mi = 0; mi < 2; ++mi)
#pragma unroll
      for (int ni = 0; ni < 2; ++ni) {
        MFMA_ACC(acc[mi + 2][ni], a[mi][0], b[ni][0]);
        MFMA_ACC(acc[mi + 2][ni], a[mi][1], b[ni][1]);
      }
    __builtin_amdgcn_s_setprio(0);
    if (t + 1 < nt) {
      if (t + 2 < nt) {
        asm volatile("s_waitcnt vmcnt(2)" ::: "memory");
      } else {
        asm volatile("s_waitcnt vmcnt(0)" ::: "memory");
      }
    }
    BARRIER();
  }

#pragma unroll
  for (int ni = 0; ni < 2; ++ni) {
    int col = n0 + wc * 32 + ni * 16 + (lane & 15);
#pragma unroll
    for (int mi = 0; mi < 4; ++mi) {
      int rbase = m0 + wr * 64 + mi * 16 + hig * 4;
#pragma unroll
      for (int r = 0; r < 4; ++r)
        C[(size_t)(rbase + r) * HID + col] = acc[mi][ni][r];
    }
  }
#undef WSTAGE_A
#undef WSTAGE_B
}

// ---------------- flash attention: swapped QK^T, exp2-domain per-lane softmax ----------------
__global__ __launch_bounds__(256) void attn_kernel(
    const bf16* __restrict__ Q, const bf16* __restrict__ Kb,
    const bf16* __restrict__ Vt, bf16* __restrict__ AO,
    float* __restrict__ Opart, float* __restrict__ Ml) {
  __shared__ bf16 Ks[64 * 128];
  __shared__ bf16 Vs[128 * 64];
  __shared__ bf16 Ps[4][16 * 64];
  const int tid = threadIdx.x, lane = tid & 63, w = tid >> 6;
  const int b = blockIdx.x;
  const int H = b & 31;
  const int tt = b >> 5;
  int qb, lo, hi, half;
  bool split;
  if (tt < 32) {
    qb = 16 + ((31 - tt) >> 1);
    half = tt & 1;
    int n = qb + 1, mid = n >> 1;
    lo = half ? mid : 0;
    hi = half ? n : mid;
    split = true;
  } else {
    qb = 47 - tt;
    half = 0;
    lo = 0;
    hi = qb + 1;
    split = false;
  }
  const int kvh = H >> 2;
  const int qw = qb * 64 + w * 16;
  const int hig = lane >> 4;
  const int q_loc = lane & 15;
  const int qa = qw + q_loc;

  bf16x8 aq[4];
#pragma unroll
  for (int kd = 0; kd < 4; ++kd) {
    int row = qw + q_loc;
    int d = kd * 32 + hig * 8;
    aq[kd] = *reinterpret_cast<const bf16x8*>(Q + (size_t)row * HID + H * HD + d);
  }

  float m_run = -1e30f, l_run = 0.0f;
  f32x4 o[8];
  const f32x4 z = {0.f, 0.f, 0.f, 0.f};
#pragma unroll
  for (int dt = 0; dt < 8; ++dt) o[dt] = z;

  for (int t = lo; t < hi; ++t) {
    int kvbase = t * 64;
#pragma unroll
    for (int it = 0; it < 4; ++it) {
      int c = w * 4 + it;
      int row = c * 4 + (lane >> 4);
      int sb = ((lane & 15) * 16) ^ ((row & 7) << 4);
      gl_lds16(Kb + (size_t)(kvbase + row) * KVDIM + kvh * HD + (sb >> 1), &Ks[c * 512]);
    }
#pragma unroll
    for (int it = 0; it < 4; ++it) {
      int c = w * 4 + it;
      int row = c * 8 + (lane >> 3);
      int sb = ((lane & 7) * 16) ^ ((row & 7) << 4);
      gl_lds16(Vt + (size_t)(kvh * HD + row) * SEQ + kvbase + (sb >> 1), &Vs[c * 512]);
    }
    __syncthreads();

    f32x4 sf[4];
#pragma unroll
    for (int j = 0; j < 4; ++j) sf[j] = z;
#pragma unroll
    for (int j = 0; j < 4; ++j) {
#pragma unroll
      for (int kd = 0; kd < 4; ++kd) {
        int r = j * 16 + q_loc;
        int byt = r * 256 + (((kd * 32 + hig * 8) * 2) ^ ((r & 7) << 4));
        bf16x8 kfr = *reinterpret_cast<const bf16x8*>(reinterpret_cast<const char*>(Ks) + byt);
        sf[j] = __builtin_amdgcn_mfma_f32_16x16x32_bf16(kfr, aq[kd], sf[j], 0, 0, 0);
      }
    }

    float vals[4][4];
    bool diag = (t == qb);
#pragma unroll
    for (int j = 0; j < 4; ++j)
#pragma unroll
      for (int r = 0; r < 4; ++r) {
        float v = sf[j][r];
        if (diag) {
          int ka = kvbase + j * 16 + hig * 4 + r;
          if (ka > qa) v = -1e30f;
        }
        vals[j][r] = v;
      }

    float m01 = fmaxf(fmaxf(vals[0][0], vals[0][1]), fmaxf(vals[0][2], vals[0][3]));
    float m23 = fmaxf(fmaxf(vals[1][0], vals[1][1]), fmaxf(vals[1][2], vals[1][3]));
    float m45 = fmaxf(fmaxf(vals[2][0], vals[2][1]), fmaxf(vals[2][2], vals[2][3]));
    float m67 = fmaxf(fmaxf(vals[3][0], vals[3][1]), fmaxf(vals[3][2], vals[3][3]));
    float m = fmaxf(fmaxf(m01, m23), fmaxf(m45, m67));
    m = fmaxf(m, __shfl_xor(m, 16));
    m = fmaxf(m, __shfl_xor(m, 32));
    float m_old = m_run;
    float mn = fmaxf(m_old, m);
    m_run = mn;
    float alpha = __builtin_exp2f(m_old - mn);

    float p[4][4];
    float rs = 0.0f;
#pragma unroll
    for (int j = 0; j < 4; ++j)
#pragma unroll
      for (int r = 0; r < 4; ++r) {
        p[j][r] = __builtin_exp2f(vals[j][r] - mn);
        rs += p[j][r];
      }
    rs += __shfl_xor(rs, 16);
    rs += __shfl_xor(rs, 32);
    l_run = l_run * alpha + rs;

#pragma unroll
    for (int j = 0; j < 4; ++j) {
      bf16 tmp[4] = {__float2bfloat16(p[j][0]), __float2bfloat16(p[j][1]),
                     __float2bfloat16(p[j][2]), __float2bfloat16(p[j][3])};
      int coff = (j * 16 + hig * 4) * 2;
      int byt = q_loc * 128 + (coff ^ ((q_loc & 7) << 4));
      *reinterpret_cast<uint2*>(reinterpret_cast<char*>(&Ps[w][0]) + byt) =
          *reinterpret_cast<const uint2*>(tmp);
    }

    if (__any(mn > m_old)) {
#pragma unroll
      for (int r = 0; r < 4; ++r) {
        float alr = __shfl(alpha, hig * 4 + r);
#pragma unroll
        for (int dt = 0; dt < 8; ++dt) o[dt][r] *= alr;
      }
    }

    bf16x8 pa[2];
#pragma unroll
    for (int ks = 0; ks < 2; ++ks) {
      int byt = q_loc * 128 + (((ks * 32 + hig * 8) * 2) ^ ((q_loc & 7) << 4));
      pa[ks] = *reinterpret_cast<const bf16x8*>(reinterpret_cast<const char*>(&Ps[w][0]) + byt);
    }
#pragma unroll
    for (int dt = 0; dt < 8; ++dt)
#pragma unroll
      for (int ks = 0; ks < 2; ++ks) {
        int vrow = dt * 16 + q_loc;
        int byt = vrow * 128 + (((ks * 32 + hig * 8) * 2) ^ ((vrow & 7) << 4));
        bf16x8 vb = *reinterpret_cast<const bf16x8*>(reinterpret_cast<const char*>(Vs) + byt);
        o[dt] = __builtin_amdgcn_mfma_f32_16x16x32_bf16(pa[ks], vb, o[dt], 0, 0, 0);
      }
    __syncthreads();
  }

  if (!split) {
#pragma unroll
    for (int r = 0; r < 4; ++r) {
      float li = __shfl(l_run, hig * 4 + r);
      float linv = 1.0f / li;
#pragma unroll
      for (int dt = 0; dt < 8; ++dt) {
        int qrow = qw + hig * 4 + r;
        int d = dt * 16 + q_loc;
        AO[(size_t)qrow * HID + H * HD + d] = __float2bfloat16(o[dt][r] * linv);
      }
    }
  } else {
    size_t pbase = ((size_t)(half * NH + H) * 1024);
#pragma unroll
    for (int dt = 0; dt < 8; ++dt)
#pragma unroll
      for (int r = 0; r < 4; ++r) {
        int qrow = qw + hig * 4 + r;
        int d = dt * 16 + q_loc;
        Opart[(pbase + (qrow - 1024)) * HD + d] = o[dt][r];
      }
    if (lane < 16) {
      Ml[(pbase + (qa - 1024)) * 2 + 0] = m_run;   // log2 domain
      Ml[(pbase + (qa - 1024)) * 2 + 1] = l_run;
    }
  }
}

// ---------------- merge split-attention partials (log2-domain m) ----------------
__global__ __launch_bounds__(256) void merge_kernel(
    const float* __restrict__ Opart, const float* __restrict__ Ml,
    bf16* __restrict__ AO) {
  int i = blockIdx.x * 256 + threadIdx.x;
  int dq = (i & 31) << 2;
  int row = (i >> 5) & 1023;
  int H = i >> 15;
  size_t b1 = (size_t)H * 1024 + row;
  size_t b2 = (size_t)(NH + H) * 1024 + row;
  float m1 = Ml[b1 * 2], l1 = Ml[b1 * 2 + 1];
  float m2 = Ml[b2 * 2], l2 = Ml[b2 * 2 + 1];
  float M = fmaxf(m1, m2);
  float w1 = __builtin_exp2f(m1 - M), w2 = __builtin_exp2f(m2 - M);
  float inv = 1.0f / (l1 * w1 + l2 * w2);
  float4 o1 = *reinterpret_cast<const float4*>(Opart + b1 * HD + dq);
  float4 o2 = *reinterpret_cast<const float4*>(Opart + b2 * HD + dq);
  bf16 o[4] = {__float2bfloat16((o1.x * w1 + o2.x * w2) * inv),
               __float2bfloat16((o1.y * w1 + o2.y * w2) * inv),
               __float2bfloat16((o1.z * w1 + o2.z * w2) * inv),
               __float2bfloat16((o1.w * w1 + o2.w * w2) * inv)};
  *reinterpret_cast<short4*>(AO + (size_t)(1024 + row) * HID + H * HD + dq) =
      *reinterpret_cast<const short4*>(o);
}

extern "C" void kernel_launch(void* const* d_in, const int* in_sizes, int n_in,
                              void* d_out, int out_size, void* d_ws, size_t ws_size,
                              hipStream_t stream) {
  const float* hidden = (const float*)d_in[0];
  const float* Wq = (const float*)d_in[2];
  const float* bq = (const float*)d_in[3];
  const float* Wk = (const float*)d_in[4];
  const float* bk = (const float*)d_in[5];
  const float* Wv = (const float*)d_in[6];
  const float* bv = (const float*)d_in[7];
  const float* Wo = (const float*)d_in[8];
  float* out = (float*)d_out;

  // workspace map (144 MiB used):
  char* ws = (char*)d_ws;
  bf16*  Wqkvt  = (bf16*)(ws + (size_t)0 * MiB);    // 48 MiB  [Q|K|V]^T bf16
  bf16*  Xb     = (bf16*)(ws + (size_t)48 * MiB);   // 16 MiB
  bf16*  Cqkvh  = (bf16*)(ws + (size_t)64 * MiB);   // 24 MiB  bf16 QKV out [64,88)
  bf16*  Wot    = (bf16*)(ws + (size_t)88 * MiB);   // 32 MiB  [88,120)
  bf16*  Qb     = (bf16*)(ws + (size_t)120 * MiB);  // 16 MiB
  bf16*  Kb     = (bf16*)(ws + (size_t)136 * MiB);  // 4 MiB
  bf16*  Vt     = (bf16*)(ws + (size_t)140 * MiB);  // 4 MiB (ends 144)
  // stream-ordered aliases:
  float* bqkv   = (float*)Qb;                       // consumed by QKV GEMM, then rope overwrites
  bf16*  AO     = Cqkvh;                            // [64,80): Cqkvh dead after postqkv
  float* Opart  = (float*)Wqkvt;                    // [0,32): Wqkvt dead after QKV GEMM
  float* Ml     = (float*)(ws + (size_t)48 * MiB);  // 0.5 MiB inside dead Xb

  concat_bias_kernel<<<QKVN / 256, 256, 0, stream>>>(bq, bk, bv, bqkv);
  transpose_all_kernel<<<49152, dim3(32, 8), 0, stream>>>(
      Wq, Wk, Wv, Wo, Wqkvt, Wot, hidden, Xb);

  // QKV GEMM: 128x192 tiles, full K, 512 blocks (2/CU), bf16 out
  qkvgemm_kernel<<<512, 512, 0, stream>>>(Xb, Wqkvt, bqkv, Cqkvh);

  // fused rope-Q (pre-scaled) / rope-K / V-transpose
  postqkv_kernel<<<12288, 256, 0, stream>>>(Cqkvh, Qb, Kb, Vt);

  attn_kernel<<<1536, 256, 0, stream>>>(Qb, Kb, Vt, AO, Opart, Ml);
  merge_kernel<<<(NH * 1024 * 32) / 256, 256, 0, stream>>>(Opart, Ml, AO);

  // Wo GEMM: 128x128 tiles, full K, 512 blocks (2/CU), fp32 direct to out
  wogemm_kernel<<<512, 512, 0, stream>>>(AO, Wot, out);
}

// Round 17
// 310.033 us; speedup vs baseline: 1.1663x; 1.1663x over previous
//
#include <hip/hip_runtime.h>
#include <hip/hip_bf16.h>

typedef __hip_bfloat16 bf16;
typedef __attribute__((ext_vector_type(8))) __bf16 bf16x8;
typedef __attribute__((ext_vector_type(4))) float f32x4;

#define SEQ 2048
#define HID 4096
#define NH 32
#define NKV 8
#define HD 128
#define KVDIM 1024
#define QKVN 6144

#define MiB (1024 * 1024)
// (1/sqrt(128)) * log2(e): folded into rope-Q so attention softmax runs in exp2 domain
#define SCALE_LOG2E 0.12751743f

__device__ __forceinline__ void gl_lds16(const void* g, void* lds) {
  __builtin_amdgcn_global_load_lds((const __attribute__((address_space(1))) void*)g,
                                   (__attribute__((address_space(3))) void*)lds,
                                   16, 0, 0);
}

__device__ __forceinline__ float unplo(unsigned u) { return __uint_as_float(u << 16); }
__device__ __forceinline__ float unphi(unsigned u) { return __uint_as_float(u & 0xffff0000u); }
__device__ __forceinline__ unsigned packbf(float a, float b) {
  bf16 t[2] = {__float2bfloat16(a), __float2bfloat16(b)};
  return *reinterpret_cast<unsigned*>(t);
}

// ---------------- bias concat [4096|1024|1024] ----------------
__global__ void concat_bias_kernel(const float* __restrict__ bq, const float* __restrict__ bk,
                                   const float* __restrict__ bv, float* __restrict__ o) {
  int i = blockIdx.x * blockDim.x + threadIdx.x;
  if (i >= QKVN) return;
  o[i] = (i < HID) ? bq[i] : (i < HID + KVDIM ? bk[i - HID] : bv[i - HID - KVDIM]);
}

// ---------------- merged weight transpose + hidden cvt ----------------
__global__ void transpose_all_kernel(const float* __restrict__ Wq, const float* __restrict__ Wk,
                                     const float* __restrict__ Wv, const float* __restrict__ Wo,
                                     bf16* __restrict__ Wqkvt, bf16* __restrict__ Wot,
                                     const float* __restrict__ hidden, bf16* __restrict__ Xb) {
  __shared__ float tile[32][33];
  int t = blockIdx.x;
  if (t >= 40960) {
    int i = ((t - 40960) * 256 + threadIdx.y * 32 + threadIdx.x) * 4;
    float4 v = *reinterpret_cast<const float4*>(hidden + i);
    bf16 o[4] = {__float2bfloat16(v.x), __float2bfloat16(v.y),
                 __float2bfloat16(v.z), __float2bfloat16(v.w)};
    *reinterpret_cast<short4*>(Xb + i) = *reinterpret_cast<const short4*>(o);
    return;
  }
  const float* in;
  bf16* out;
  int si, xt, yt;
  if (t < 16384)      { in = Wq; out = Wqkvt;                           si = HID;   xt = t & 127; yt = t >> 7; }
  else if (t < 20480) { t -= 16384; in = Wk; out = Wqkvt + (size_t)HID * HID;           si = KVDIM; xt = t & 31; yt = t >> 5; }
  else if (t < 24576) { t -= 20480; in = Wv; out = Wqkvt + (size_t)(HID + KVDIM) * HID; si = KVDIM; xt = t & 31; yt = t >> 5; }
  else                { t -= 24576; in = Wo; out = Wot;                 si = HID;   xt = t & 127; yt = t >> 7; }
  int c0 = xt * 32, r0 = yt * 32;
  int tx = threadIdx.x, ty = threadIdx.y;
#pragma unroll
  for (int i = 0; i < 32; i += 8)
    tile[ty + i][tx] = in[(size_t)(r0 + ty + i) * si + (c0 + tx)];
  __syncthreads();
#pragma unroll
  for (int i = 0; i < 32; i += 8)
    out[(size_t)(c0 + ty + i) * HID + (r0 + tx)] = __float2bfloat16(tile[tx][ty + i]);
}

// ---------------- fused post-QKV: rope Q (pre-scaled), rope K, V transpose ----------------
__global__ void postqkv_kernel(const bf16* __restrict__ Ch, bf16* __restrict__ Qb,
                               bf16* __restrict__ Kb, bf16* __restrict__ Vt) {
  __shared__ float tile[32][33];
  int b = blockIdx.x;
  int tid = threadIdx.x;
  if (b < 10240) {
    bool isQ = (b < 8192);
    int idx = (isQ ? b : b - 8192) * 256 + tid;
    int j = idx & 31;
    int h = (idx >> 5) & (isQ ? 31 : 7);
    int s = idx >> (isQ ? 10 : 8);
    size_t bi = (size_t)s * QKVN + (isQ ? 0 : HID) + h * HD;
    unsigned u1 = *reinterpret_cast<const unsigned*>(Ch + bi + 2 * j);
    unsigned u2 = *reinterpret_cast<const unsigned*>(Ch + bi + 64 + 2 * j);
    float x1a = unplo(u1), x1b = unphi(u1);
    float x2a = unplo(u2), x2b = unphi(u2);
    float inv0 = __expf(-(float)(2 * j) * 0.14391156831212787f);
    float inv1 = __expf(-(float)(2 * j + 1) * 0.14391156831212787f);
    float sn0, cs0, sn1, cs1;
    __sincosf((float)s * inv0, &sn0, &cs0);
    __sincosf((float)s * inv1, &sn1, &cs1);
    if (isQ) {
      cs0 *= SCALE_LOG2E; sn0 *= SCALE_LOG2E;
      cs1 *= SCALE_LOG2E; sn1 *= SCALE_LOG2E;
    }
    size_t bo = (size_t)s * (isQ ? HID : KVDIM) + h * HD;
    bf16* Ob = isQ ? Qb : Kb;
    *reinterpret_cast<unsigned*>(Ob + bo + 2 * j) =
        packbf(x1a * cs0 - x2a * sn0, x1b * cs1 - x2b * sn1);
    *reinterpret_cast<unsigned*>(Ob + bo + 64 + 2 * j) =
        packbf(x2a * cs0 + x1a * sn0, x2b * cs1 + x1b * sn1);
  } else {
    int t = b - 10240;
    int xt = t & 31, yt = t >> 5;
    int tx = tid & 31, ty = tid >> 5;
#pragma unroll
    for (int i = 0; i < 32; i += 8)
      tile[ty + i][tx] = __bfloat162float(Ch[(size_t)(yt * 32 + ty + i) * QKVN + (HID + KVDIM) + xt * 32 + tx]);
    __syncthreads();
#pragma unroll
    for (int i = 0; i < 32; i += 8)
      Vt[(size_t)(xt * 32 + ty + i) * SEQ + (yt * 32 + tx)] = __float2bfloat16(tile[tx][ty + i]);
  }
}

#define BARRIER() __builtin_amdgcn_s_barrier()
#define LGKM0()                                          \
  {                                                      \
    asm volatile("s_waitcnt lgkmcnt(0)" ::: "memory");   \
    __builtin_amdgcn_sched_barrier(0);                   \
  }
#define MFMA_ACC(d, x, y) d = __builtin_amdgcn_mfma_f32_16x16x32_bf16(x, y, d, 0, 0, 0)

// ---------------- QKV GEMM: 256x192 tile, full K, 256 blocks, 2-phase pipelined ----------------
__global__ __launch_bounds__(512, 2) void qkvgemm_kernel(
    const bf16* __restrict__ A,   // [SEQ][HID]
    const bf16* __restrict__ Bt,  // [QKVN][HID]
    const float* __restrict__ bias,
    bf16* __restrict__ Ch) {      // [SEQ][QKVN]
  __shared__ bf16 lds[2][448 * 64];  // A rows [0,256), B rows [256,448)
  const int blk = blockIdx.x;
  const int sw = (blk & 7) * 32 + (blk >> 3);   // bijective XCD swizzle (256 = 8*32)
  const int bx = sw & 31, by = sw >> 5;
  const int n0 = bx * 192;
  const int m0 = by * 256;
  const int tid = threadIdx.x;
  const int lane = tid & 63;
  const int w = tid >> 6;
  const int wr = w >> 2, wc = w & 3;            // 2M x 4N
  const int hig = lane >> 4;
  const int nt = HID / 64;                       // 64

#define QSTAGE_A(buf, t)                                                          \
  {                                                                               \
    _Pragma("unroll")                                                             \
    for (int _c = 0; _c < 4; ++_c) {                                              \
      int _row = _c * 64 + w * 8 + (lane >> 3);                                   \
      int _ch = (lane & 7) ^ ((lane >> 3) & 7);                                   \
      gl_lds16(A + (size_t)(m0 + _row) * HID + (size_t)(t) * 64 + _ch * 8,        \
               &lds[buf][(_c * 64 + w * 8) * 64]);                                \
    }                                                                             \
  }
#define QSTAGE_B(buf, t)                                                          \
  {                                                                               \
    _Pragma("unroll")                                                             \
    for (int _c = 0; _c < 3; ++_c) {                                              \
      int _row = _c * 64 + w * 8 + (lane >> 3);                                   \
      int _ch = (lane & 7) ^ ((lane >> 3) & 7);                                   \
      gl_lds16(Bt + (size_t)(n0 + _row) * HID + (size_t)(t) * 64 + _ch * 8,       \
               &lds[buf][(256 + _c * 64 + w * 8) * 64]);                          \
    }                                                                             \
  }

  auto rdA = [&](int cur, int mi, int ks) {
    int rr = wr * 128 + mi * 16 + (lane & 15);
    int byt = rr * 128 + (((ks * 32 + hig * 8) * 2) ^ ((rr & 7) << 4));
    return *reinterpret_cast<const bf16x8*>(
        reinterpret_cast<const char*>(&lds[cur][0]) + byt);
  };
  auto rdB = [&](int cur, int ni, int ks) {
    int rr = wc * 48 + ni * 16 + (lane & 15);
    int byt = 32768 + rr * 128 + (((ks * 32 + hig * 8) * 2) ^ ((rr & 7) << 4));
    return *reinterpret_cast<const bf16x8*>(
        reinterpret_cast<const char*>(&lds[cur][0]) + byt);
  };

  f32x4 acc[8][3];
  const f32x4 z = {0.f, 0.f, 0.f, 0.f};
#pragma unroll
  for (int i = 0; i < 8; ++i)
#pragma unroll
    for (int j = 0; j < 3; ++j) acc[i][j] = z;

  QSTAGE_A(0, 0); QSTAGE_B(0, 0);
  QSTAGE_B(1, 1);
  asm volatile("s_waitcnt vmcnt(3)" ::: "memory");
  BARRIER();

  bf16x8 a[4][2], b[3][2];
  int cur = 0;
  for (int t = 0; t < nt; ++t, cur ^= 1) {
#pragma unroll
    for (int mi = 0; mi < 4; ++mi) { a[mi][0] = rdA(cur, mi, 0); a[mi][1] = rdA(cur, mi, 1); }
#pragma unroll
    for (int ni = 0; ni < 3; ++ni) { b[ni][0] = rdB(cur, ni, 0); b[ni][1] = rdB(cur, ni, 1); }
    if (t + 1 < nt) QSTAGE_A(cur ^ 1, t + 1);
    LGKM0();
    __builtin_amdgcn_s_setprio(1);
#pragma unroll
    for (int mi = 0; mi < 4; ++mi)
#pragma unroll
      for (int ni = 0; ni < 3; ++ni) {
        MFMA_ACC(acc[mi][ni], a[mi][0], b[ni][0]);
        MFMA_ACC(acc[mi][ni], a[mi][1], b[ni][1]);
      }
    __builtin_amdgcn_s_setprio(0);
    BARRIER();
#pragma unroll
    for (int mi = 0; mi < 4; ++mi) { a[mi][0] = rdA(cur, mi + 4, 0); a[mi][1] = rdA(cur, mi + 4, 1); }
    if (t + 2 < nt) QSTAGE_B(cur, t + 2);
    LGKM0();
    __builtin_amdgcn_s_setprio(1);
#pragma unroll
    for (int mi = 0; mi < 4; ++mi)
#pragma unroll
      for (int ni = 0; ni < 3; ++ni) {
        MFMA_ACC(acc[mi + 4][ni], a[mi][0], b[ni][0]);
        MFMA_ACC(acc[mi + 4][ni], a[mi][1], b[ni][1]);
      }
    __builtin_amdgcn_s_setprio(0);
    if (t + 1 < nt) {
      if (t + 2 < nt) {
        asm volatile("s_waitcnt vmcnt(3)" ::: "memory");
      } else {
        asm volatile("s_waitcnt vmcnt(0)" ::: "memory");
      }
    }
    BARRIER();
  }

#pragma unroll
  for (int ni = 0; ni < 3; ++ni) {
    int col = n0 + wc * 48 + ni * 16 + (lane & 15);
    float bv = bias[col];
#pragma unroll
    for (int mi = 0; mi < 8; ++mi) {
      int rbase = m0 + wr * 128 + mi * 16 + hig * 4;
#pragma unroll
      for (int r = 0; r < 4; ++r)
        Ch[(size_t)(rbase + r) * QKVN + col] = __float2bfloat16(acc[mi][ni][r] + bv);
    }
  }
#undef QSTAGE_A
#undef QSTAGE_B
}

// ---------------- Wo GEMM: 256x128 tile, full K, 256 blocks, 2-phase pipelined ----------------
__global__ __launch_bounds__(512, 2) void wogemm_kernel(
    const bf16* __restrict__ A,   // [SEQ][HID]
    const bf16* __restrict__ Bt,  // [HID][HID]
    float* __restrict__ C) {      // [SEQ][HID]
  __shared__ bf16 lds[2][3][128 * 64];  // [buf][A0,A1,B]
  const int blk = blockIdx.x;
  const int sw = (blk & 7) * 32 + (blk >> 3);
  const int n0 = (sw & 31) * 128;
  const int m0 = (sw >> 5) * 256;
  const int tid = threadIdx.x;
  const int lane = tid & 63;
  const int w = tid >> 6;
  const int wr = w >> 1, wc = w & 1;
  const int nt = HID / 64;

#define WSTAGE(buf, slot, t)                                                    \
  {                                                                             \
    const bf16* _s = ((slot) == 2) ? Bt : A;                                    \
    int _g0 = ((slot) == 2) ? n0 : (m0 + (slot) * 128);                         \
    _Pragma("unroll")                                                           \
    for (int _it = 0; _it < 2; ++_it) {                                         \
      int _row = w * 16 + _it * 8 + (lane >> 3);                                \
      int _ch = (lane & 7) ^ (_row & 7);                                        \
      gl_lds16(_s + (size_t)(_g0 + _row) * HID + (size_t)(t) * 64 + _ch * 8,    \
               &lds[buf][slot][(w * 16 + _it * 8) * 64]);                       \
    }                                                                           \
  }

  auto rdA = [&](int cur, int mi, int ks) {
    int rr = (wr & 1) * 64 + mi * 16 + (lane & 15);
    int byt = rr * 128 + (((ks * 32 + (lane >> 4) * 8) * 2) ^ ((rr & 7) << 4));
    return *reinterpret_cast<const bf16x8*>(
        reinterpret_cast<const char*>(&lds[cur][wr >> 1][0]) + byt);
  };
  auto rdB = [&](int cur, int ni, int ks) {
    int rr = wc * 64 + ni * 16 + (lane & 15);
    int byt = rr * 128 + (((ks * 32 + (lane >> 4) * 8) * 2) ^ ((rr & 7) << 4));
    return *reinterpret_cast<const bf16x8*>(
        reinterpret_cast<const char*>(&lds[cur][2][0]) + byt);
  };

  f32x4 acc[4][4];
  const f32x4 z = {0.f, 0.f, 0.f, 0.f};
#pragma unroll
  for (int i = 0; i < 4; ++i)
#pragma unroll
    for (int j = 0; j < 4; ++j) acc[i][j] = z;

  WSTAGE(0, 0, 0); WSTAGE(0, 1, 0); WSTAGE(0, 2, 0);
  WSTAGE(1, 2, 1);
  asm volatile("s_waitcnt vmcnt(2)" ::: "memory");
  BARRIER();

  bf16x8 a[2][2], b[4][2];
  int cur = 0;
  for (int t = 0; t < nt; ++t, cur ^= 1) {
#pragma unroll
    for (int mi = 0; mi < 2; ++mi) { a[mi][0] = rdA(cur, mi, 0); a[mi][1] = rdA(cur, mi, 1); }
#pragma unroll
    for (int ni = 0; ni < 4; ++ni) { b[ni][0] = rdB(cur, ni, 0); b[ni][1] = rdB(cur, ni, 1); }
    if (t + 1 < nt) { WSTAGE(cur ^ 1, 0, t + 1); WSTAGE(cur ^ 1, 1, t + 1); }
    LGKM0();
    __builtin_amdgcn_s_setprio(1);
#pragma unroll
    for (int mi = 0; mi < 2; ++mi)
#pragma unroll
      for (int ni = 0; ni < 4; ++ni) {
        MFMA_ACC(acc[mi][ni], a[mi][0], b[ni][0]);
        MFMA_ACC(acc[mi][ni], a[mi][1], b[ni][1]);
      }
    __builtin_amdgcn_s_setprio(0);
    BARRIER();
#pragma unroll
    for (int mi = 0; mi < 2; ++mi) { a[mi][0] = rdA(cur, mi + 2, 0); a[mi][1] = rdA(cur, mi + 2, 1); }
    if (t + 2 < nt) WSTAGE(cur, 2, t + 2);
    LGKM0();
    __builtin_amdgcn_s_setprio(1);
#pragma unroll
    for (int mi = 0; mi < 2; ++mi)
#pragma unroll
      for (int ni = 0; ni < 4; ++ni) {
        MFMA_ACC(acc[mi + 2][ni], a[mi][0], b[ni][0]);
        MFMA_ACC(acc[mi + 2][ni], a[mi][1], b[ni][1]);
      }
    __builtin_amdgcn_s_setprio(0);
    if (t + 1 < nt) {
      if (t + 2 < nt) {
        asm volatile("s_waitcnt vmcnt(2)" ::: "memory");
      } else {
        asm volatile("s_waitcnt vmcnt(0)" ::: "memory");
      }
    }
    BARRIER();
  }

#pragma unroll
  for (int ni = 0; ni < 4; ++ni) {
    int col = n0 + wc * 64 + ni * 16 + (lane & 15);
#pragma unroll
    for (int mi = 0; mi < 4; ++mi) {
      int rbase = m0 + wr * 64 + mi * 16 + (lane >> 4) * 4;
#pragma unroll
      for (int r = 0; r < 4; ++r)
        C[(size_t)(rbase + r) * HID + col] = acc[mi][ni][r];
    }
  }
#undef WSTAGE
}

// ---------------- flash attention: paired q-tiles (qb=pr and qb=31-pr), no split ----------------
// grid 512: H = b&31, pr = b>>5 in [0,16). Each block does exactly 33 tile-iters.
__global__ __launch_bounds__(256) void attn_kernel(
    const bf16* __restrict__ Q, const bf16* __restrict__ Kb,
    const bf16* __restrict__ Vt, bf16* __restrict__ AO) {
  __shared__ bf16 Ks[64 * 128];
  __shared__ bf16 Vs[128 * 64];
  __shared__ bf16 Ps[4][16 * 64];
  const int tid = threadIdx.x, lane = tid & 63, w = tid >> 6;
  const int b = blockIdx.x;
  const int H = b & 31;
  const int pr = b >> 5;
  const int kvh = H >> 2;
  const int hig = lane >> 4;
  const int q_loc = lane & 15;
  const f32x4 z = {0.f, 0.f, 0.f, 0.f};

#pragma unroll
  for (int pass = 0; pass < 2; ++pass) {
    const int qb = pass ? (31 - pr) : pr;
    const int qw = qb * 64 + w * 16;
    const int qa = qw + q_loc;

    bf16x8 aq[4];
#pragma unroll
    for (int kd = 0; kd < 4; ++kd) {
      int row = qw + q_loc;
      int d = kd * 32 + hig * 8;
      aq[kd] = *reinterpret_cast<const bf16x8*>(Q + (size_t)row * HID + H * HD + d);
    }

    float m_run = -1e30f, l_run = 0.0f;
    f32x4 o[8];
#pragma unroll
    for (int dt = 0; dt < 8; ++dt) o[dt] = z;

    for (int t = 0; t <= qb; ++t) {
      int kvbase = t * 64;
#pragma unroll
      for (int it = 0; it < 4; ++it) {
        int c = w * 4 + it;
        int row = c * 4 + (lane >> 4);
        int sb = ((lane & 15) * 16) ^ ((row & 7) << 4);
        gl_lds16(Kb + (size_t)(kvbase + row) * KVDIM + kvh * HD + (sb >> 1), &Ks[c * 512]);
      }
#pragma unroll
      for (int it = 0; it < 4; ++it) {
        int c = w * 4 + it;
        int row = c * 8 + (lane >> 3);
        int sb = ((lane & 7) * 16) ^ ((row & 7) << 4);
        gl_lds16(Vt + (size_t)(kvh * HD + row) * SEQ + kvbase + (sb >> 1), &Vs[c * 512]);
      }
      __syncthreads();

      f32x4 sf[4];
#pragma unroll
      for (int j = 0; j < 4; ++j) sf[j] = z;
#pragma unroll
      for (int j = 0; j < 4; ++j) {
#pragma unroll
        for (int kd = 0; kd < 4; ++kd) {
          int r = j * 16 + q_loc;
          int byt = r * 256 + (((kd * 32 + hig * 8) * 2) ^ ((r & 7) << 4));
          bf16x8 kfr = *reinterpret_cast<const bf16x8*>(reinterpret_cast<const char*>(Ks) + byt);
          sf[j] = __builtin_amdgcn_mfma_f32_16x16x32_bf16(kfr, aq[kd], sf[j], 0, 0, 0);
        }
      }

      float vals[4][4];
      bool diag = (t == qb);
#pragma unroll
      for (int j = 0; j < 4; ++j)
#pragma unroll
        for (int r = 0; r < 4; ++r) {
          float v = sf[j][r];
          if (diag) {
            int ka = kvbase + j * 16 + hig * 4 + r;
            if (ka > qa) v = -1e30f;
          }
          vals[j][r] = v;
        }

      float m01 = fmaxf(fmaxf(vals[0][0], vals[0][1]), fmaxf(vals[0][2], vals[0][3]));
      float m23 = fmaxf(fmaxf(vals[1][0], vals[1][1]), fmaxf(vals[1][2], vals[1][3]));
      float m45 = fmaxf(fmaxf(vals[2][0], vals[2][1]), fmaxf(vals[2][2], vals[2][3]));
      float m67 = fmaxf(fmaxf(vals[3][0], vals[3][1]), fmaxf(vals[3][2], vals[3][3]));
      float m = fmaxf(fmaxf(m01, m23), fmaxf(m45, m67));
      m = fmaxf(m, __shfl_xor(m, 16));
      m = fmaxf(m, __shfl_xor(m, 32));
      float m_old = m_run;
      float mn = fmaxf(m_old, m);
      m_run = mn;
      float alpha = __builtin_exp2f(m_old - mn);

      float p[4][4];
      float rs = 0.0f;
#pragma unroll
      for (int j = 0; j < 4; ++j)
#pragma unroll
        for (int r = 0; r < 4; ++r) {
          p[j][r] = __builtin_exp2f(vals[j][r] - mn);
          rs += p[j][r];
        }
      rs += __shfl_xor(rs, 16);
      rs += __shfl_xor(rs, 32);
      l_run = l_run * alpha + rs;

#pragma unroll
      for (int j = 0; j < 4; ++j) {
        bf16 tmp[4] = {__float2bfloat16(p[j][0]), __float2bfloat16(p[j][1]),
                       __float2bfloat16(p[j][2]), __float2bfloat16(p[j][3])};
        int coff = (j * 16 + hig * 4) * 2;
        int byt = q_loc * 128 + (coff ^ ((q_loc & 7) << 4));
        *reinterpret_cast<uint2*>(reinterpret_cast<char*>(&Ps[w][0]) + byt) =
            *reinterpret_cast<const uint2*>(tmp);
      }

      if (__any(mn > m_old)) {
#pragma unroll
        for (int r = 0; r < 4; ++r) {
          float alr = __shfl(alpha, hig * 4 + r);
#pragma unroll
          for (int dt = 0; dt < 8; ++dt) o[dt][r] *= alr;
        }
      }

      bf16x8 pa[2];
#pragma unroll
      for (int ks = 0; ks < 2; ++ks) {
        int byt = q_loc * 128 + (((ks * 32 + hig * 8) * 2) ^ ((q_loc & 7) << 4));
        pa[ks] = *reinterpret_cast<const bf16x8*>(reinterpret_cast<const char*>(&Ps[w][0]) + byt);
      }
#pragma unroll
      for (int dt = 0; dt < 8; ++dt)
#pragma unroll
        for (int ks = 0; ks < 2; ++ks) {
          int vrow = dt * 16 + q_loc;
          int byt = vrow * 128 + (((ks * 32 + hig * 8) * 2) ^ ((vrow & 7) << 4));
          bf16x8 vb = *reinterpret_cast<const bf16x8*>(reinterpret_cast<const char*>(Vs) + byt);
          o[dt] = __builtin_amdgcn_mfma_f32_16x16x32_bf16(pa[ks], vb, o[dt], 0, 0, 0);
        }
      __syncthreads();
    }

#pragma unroll
    for (int r = 0; r < 4; ++r) {
      float li = __shfl(l_run, hig * 4 + r);
      float linv = 1.0f / li;
#pragma unroll
      for (int dt = 0; dt < 8; ++dt) {
        int qrow = qw + hig * 4 + r;
        int d = dt * 16 + q_loc;
        AO[(size_t)qrow * HID + H * HD + d] = __float2bfloat16(o[dt][r] * linv);
      }
    }
  }
}

extern "C" void kernel_launch(void* const* d_in, const int* in_sizes, int n_in,
                              void* d_out, int out_size, void* d_ws, size_t ws_size,
                              hipStream_t stream) {
  const float* hidden = (const float*)d_in[0];
  const float* Wq = (const float*)d_in[2];
  const float* bq = (const float*)d_in[3];
  const float* Wk = (const float*)d_in[4];
  const float* bk = (const float*)d_in[5];
  const float* Wv = (const float*)d_in[6];
  const float* bv = (const float*)d_in[7];
  const float* Wo = (const float*)d_in[8];
  float* out = (float*)d_out;

  // workspace map (144 MiB used):
  char* ws = (char*)d_ws;
  bf16*  Wqkvt  = (bf16*)(ws + (size_t)0 * MiB);    // 48 MiB  [Q|K|V]^T bf16
  bf16*  Xb     = (bf16*)(ws + (size_t)48 * MiB);   // 16 MiB
  bf16*  Cqkvh  = (bf16*)(ws + (size_t)64 * MiB);   // 24 MiB  bf16 QKV out [64,88)
  bf16*  Wot    = (bf16*)(ws + (size_t)88 * MiB);   // 32 MiB  [88,120)
  bf16*  Qb     = (bf16*)(ws + (size_t)120 * MiB);  // 16 MiB
  bf16*  Kb     = (bf16*)(ws + (size_t)136 * MiB);  // 4 MiB
  bf16*  Vt     = (bf16*)(ws + (size_t)140 * MiB);  // 4 MiB (ends 144)
  // stream-ordered aliases:
  float* bqkv   = (float*)Qb;                       // consumed by QKV GEMM, then rope overwrites
  bf16*  AO     = Cqkvh;                            // [64,80): Cqkvh dead after postqkv

  concat_bias_kernel<<<QKVN / 256, 256, 0, stream>>>(bq, bk, bv, bqkv);
  transpose_all_kernel<<<49152, dim3(32, 8), 0, stream>>>(
      Wq, Wk, Wv, Wo, Wqkvt, Wot, hidden, Xb);

  // QKV GEMM: 256x192 tiles, full K, 256 blocks, bf16 out
  qkvgemm_kernel<<<256, 512, 0, stream>>>(Xb, Wqkvt, bqkv, Cqkvh);

  // fused rope-Q (pre-scaled) / rope-K / V-transpose
  postqkv_kernel<<<12288, 256, 0, stream>>>(Cqkvh, Qb, Kb, Vt);

  // paired-q-tile attention: 512 blocks, exactly 33 tile-iters each
  attn_kernel<<<512, 256, 0, stream>>>(Qb, Kb, Vt, AO);

  // Wo GEMM: 256x128 tiles, full K, 256 blocks, fp32 direct to out
  wogemm_kernel<<<256, 512, 0, stream>>>(AO, Wot, out);
}

// Round 18
// 308.014 us; speedup vs baseline: 1.1740x; 1.0066x over previous
//
#include <hip/hip_runtime.h>
#include <hip/hip_bf16.h>

typedef __hip_bfloat16 bf16;
typedef __attribute__((ext_vector_type(8))) __bf16 bf16x8;
typedef __attribute__((ext_vector_type(4))) float f32x4;

#define SEQ 2048
#define HID 4096
#define NH 32
#define NKV 8
#define HD 128
#define KVDIM 1024
#define QKVN 6144

#define MiB (1024 * 1024)
// (1/sqrt(128)) * log2(e): folded into rope-Q so attention softmax runs in exp2 domain
#define SCALE_LOG2E 0.12751743f

__device__ __forceinline__ void gl_lds16(const void* g, void* lds) {
  __builtin_amdgcn_global_load_lds((const __attribute__((address_space(1))) void*)g,
                                   (__attribute__((address_space(3))) void*)lds,
                                   16, 0, 0);
}

__device__ __forceinline__ float unplo(unsigned u) { return __uint_as_float(u << 16); }
__device__ __forceinline__ float unphi(unsigned u) { return __uint_as_float(u & 0xffff0000u); }
__device__ __forceinline__ unsigned packbf(float a, float b) {
  bf16 t[2] = {__float2bfloat16(a), __float2bfloat16(b)};
  return *reinterpret_cast<unsigned*>(t);
}

// ---------------- bias concat [4096|1024|1024] ----------------
__global__ void concat_bias_kernel(const float* __restrict__ bq, const float* __restrict__ bk,
                                   const float* __restrict__ bv, float* __restrict__ o) {
  int i = blockIdx.x * blockDim.x + threadIdx.x;
  if (i >= QKVN) return;
  o[i] = (i < HID) ? bq[i] : (i < HID + KVDIM ? bk[i - HID] : bv[i - HID - KVDIM]);
}

// ---------------- merged weight transpose + hidden cvt ----------------
__global__ void transpose_all_kernel(const float* __restrict__ Wq, const float* __restrict__ Wk,
                                     const float* __restrict__ Wv, const float* __restrict__ Wo,
                                     bf16* __restrict__ Wqkvt, bf16* __restrict__ Wot,
                                     const float* __restrict__ hidden, bf16* __restrict__ Xb) {
  __shared__ float tile[32][33];
  int t = blockIdx.x;
  if (t >= 40960) {
    int i = ((t - 40960) * 256 + threadIdx.y * 32 + threadIdx.x) * 4;
    float4 v = *reinterpret_cast<const float4*>(hidden + i);
    bf16 o[4] = {__float2bfloat16(v.x), __float2bfloat16(v.y),
                 __float2bfloat16(v.z), __float2bfloat16(v.w)};
    *reinterpret_cast<short4*>(Xb + i) = *reinterpret_cast<const short4*>(o);
    return;
  }
  const float* in;
  bf16* out;
  int si, xt, yt;
  if (t < 16384)      { in = Wq; out = Wqkvt;                           si = HID;   xt = t & 127; yt = t >> 7; }
  else if (t < 20480) { t -= 16384; in = Wk; out = Wqkvt + (size_t)HID * HID;           si = KVDIM; xt = t & 31; yt = t >> 5; }
  else if (t < 24576) { t -= 20480; in = Wv; out = Wqkvt + (size_t)(HID + KVDIM) * HID; si = KVDIM; xt = t & 31; yt = t >> 5; }
  else                { t -= 24576; in = Wo; out = Wot;                 si = HID;   xt = t & 127; yt = t >> 7; }
  int c0 = xt * 32, r0 = yt * 32;
  int tx = threadIdx.x, ty = threadIdx.y;
#pragma unroll
  for (int i = 0; i < 32; i += 8)
    tile[ty + i][tx] = in[(size_t)(r0 + ty + i) * si + (c0 + tx)];
  __syncthreads();
#pragma unroll
  for (int i = 0; i < 32; i += 8)
    out[(size_t)(c0 + ty + i) * HID + (r0 + tx)] = __float2bfloat16(tile[tx][ty + i]);
}

// ---------------- fused post-QKV: rope Q (pre-scaled), rope K, V transpose ----------------
__global__ void postqkv_kernel(const bf16* __restrict__ Ch, bf16* __restrict__ Qb,
                               bf16* __restrict__ Kb, bf16* __restrict__ Vt) {
  __shared__ float tile[32][33];
  int b = blockIdx.x;
  int tid = threadIdx.x;
  if (b < 10240) {
    bool isQ = (b < 8192);
    int idx = (isQ ? b : b - 8192) * 256 + tid;
    int j = idx & 31;
    int h = (idx >> 5) & (isQ ? 31 : 7);
    int s = idx >> (isQ ? 10 : 8);
    size_t bi = (size_t)s * QKVN + (isQ ? 0 : HID) + h * HD;
    unsigned u1 = *reinterpret_cast<const unsigned*>(Ch + bi + 2 * j);
    unsigned u2 = *reinterpret_cast<const unsigned*>(Ch + bi + 64 + 2 * j);
    float x1a = unplo(u1), x1b = unphi(u1);
    float x2a = unplo(u2), x2b = unphi(u2);
    float inv0 = __expf(-(float)(2 * j) * 0.14391156831212787f);
    float inv1 = __expf(-(float)(2 * j + 1) * 0.14391156831212787f);
    float sn0, cs0, sn1, cs1;
    __sincosf((float)s * inv0, &sn0, &cs0);
    __sincosf((float)s * inv1, &sn1, &cs1);
    if (isQ) {
      cs0 *= SCALE_LOG2E; sn0 *= SCALE_LOG2E;
      cs1 *= SCALE_LOG2E; sn1 *= SCALE_LOG2E;
    }
    size_t bo = (size_t)s * (isQ ? HID : KVDIM) + h * HD;
    bf16* Ob = isQ ? Qb : Kb;
    *reinterpret_cast<unsigned*>(Ob + bo + 2 * j) =
        packbf(x1a * cs0 - x2a * sn0, x1b * cs1 - x2b * sn1);
    *reinterpret_cast<unsigned*>(Ob + bo + 64 + 2 * j) =
        packbf(x2a * cs0 + x1a * sn0, x2b * cs1 + x1b * sn1);
  } else {
    int t = b - 10240;
    int xt = t & 31, yt = t >> 5;
    int tx = tid & 31, ty = tid >> 5;
#pragma unroll
    for (int i = 0; i < 32; i += 8)
      tile[ty + i][tx] = __bfloat162float(Ch[(size_t)(yt * 32 + ty + i) * QKVN + (HID + KVDIM) + xt * 32 + tx]);
    __syncthreads();
#pragma unroll
    for (int i = 0; i < 32; i += 8)
      Vt[(size_t)(xt * 32 + ty + i) * SEQ + (yt * 32 + tx)] = __float2bfloat16(tile[tx][ty + i]);
  }
}

#define BARRIER() __builtin_amdgcn_s_barrier()
#define LGKM0()                                          \
  {                                                      \
    asm volatile("s_waitcnt lgkmcnt(0)" ::: "memory");   \
    __builtin_amdgcn_sched_barrier(0);                   \
  }
#define MFMA_ACC(d, x, y) d = __builtin_amdgcn_mfma_f32_16x16x32_bf16(x, y, d, 0, 0, 0)

// ---------------- QKV GEMM: 256x192 tile, full K, 256 blocks, 2-phase pipelined ----------------
// XCD column-strip swizzle: each XCD owns 4 bx x 8 by -> B panels L2-shared within
// one XCD; A is L3-resident (16 MB) read once from HBM.
__global__ __launch_bounds__(512, 2) void qkvgemm_kernel(
    const bf16* __restrict__ A,   // [SEQ][HID]
    const bf16* __restrict__ Bt,  // [QKVN][HID]
    const float* __restrict__ bias,
    bf16* __restrict__ Ch) {      // [SEQ][QKVN]
  __shared__ bf16 lds[2][448 * 64];  // A rows [0,256), B rows [256,448)
  const int blk = blockIdx.x;
  const int xcd = blk & 7, loc = blk >> 3;
  const int bx = xcd * 4 + (loc & 3);   // [0,32)
  const int by = loc >> 2;              // [0,8)
  const int n0 = bx * 192;
  const int m0 = by * 256;
  const int tid = threadIdx.x;
  const int lane = tid & 63;
  const int w = tid >> 6;
  const int wr = w >> 2, wc = w & 3;            // 2M x 4N
  const int hig = lane >> 4;
  const int nt = HID / 64;                       // 64

#define QSTAGE_A(buf, t)                                                          \
  {                                                                               \
    _Pragma("unroll")                                                             \
    for (int _c = 0; _c < 4; ++_c) {                                              \
      int _row = _c * 64 + w * 8 + (lane >> 3);                                   \
      int _ch = (lane & 7) ^ ((lane >> 3) & 7);                                   \
      gl_lds16(A + (size_t)(m0 + _row) * HID + (size_t)(t) * 64 + _ch * 8,        \
               &lds[buf][(_c * 64 + w * 8) * 64]);                                \
    }                                                                             \
  }
#define QSTAGE_B(buf, t)                                                          \
  {                                                                               \
    _Pragma("unroll")                                                             \
    for (int _c = 0; _c < 3; ++_c) {                                              \
      int _row = _c * 64 + w * 8 + (lane >> 3);                                   \
      int _ch = (lane & 7) ^ ((lane >> 3) & 7);                                   \
      gl_lds16(Bt + (size_t)(n0 + _row) * HID + (size_t)(t) * 64 + _ch * 8,       \
               &lds[buf][(256 + _c * 64 + w * 8) * 64]);                          \
    }                                                                             \
  }

  auto rdA = [&](int cur, int mi, int ks) {
    int rr = wr * 128 + mi * 16 + (lane & 15);
    int byt = rr * 128 + (((ks * 32 + hig * 8) * 2) ^ ((rr & 7) << 4));
    return *reinterpret_cast<const bf16x8*>(
        reinterpret_cast<const char*>(&lds[cur][0]) + byt);
  };
  auto rdB = [&](int cur, int ni, int ks) {
    int rr = wc * 48 + ni * 16 + (lane & 15);
    int byt = 32768 + rr * 128 + (((ks * 32 + hig * 8) * 2) ^ ((rr & 7) << 4));
    return *reinterpret_cast<const bf16x8*>(
        reinterpret_cast<const char*>(&lds[cur][0]) + byt);
  };

  f32x4 acc[8][3];
  const f32x4 z = {0.f, 0.f, 0.f, 0.f};
#pragma unroll
  for (int i = 0; i < 8; ++i)
#pragma unroll
    for (int j = 0; j < 3; ++j) acc[i][j] = z;

  QSTAGE_A(0, 0); QSTAGE_B(0, 0);
  QSTAGE_B(1, 1);
  asm volatile("s_waitcnt vmcnt(3)" ::: "memory");
  BARRIER();

  bf16x8 a[4][2], b[3][2];
  int cur = 0;
  for (int t = 0; t < nt; ++t, cur ^= 1) {
#pragma unroll
    for (int mi = 0; mi < 4; ++mi) { a[mi][0] = rdA(cur, mi, 0); a[mi][1] = rdA(cur, mi, 1); }
#pragma unroll
    for (int ni = 0; ni < 3; ++ni) { b[ni][0] = rdB(cur, ni, 0); b[ni][1] = rdB(cur, ni, 1); }
    if (t + 1 < nt) QSTAGE_A(cur ^ 1, t + 1);
    LGKM0();
    __builtin_amdgcn_s_setprio(1);
#pragma unroll
    for (int mi = 0; mi < 4; ++mi)
#pragma unroll
      for (int ni = 0; ni < 3; ++ni) {
        MFMA_ACC(acc[mi][ni], a[mi][0], b[ni][0]);
        MFMA_ACC(acc[mi][ni], a[mi][1], b[ni][1]);
      }
    __builtin_amdgcn_s_setprio(0);
    BARRIER();
#pragma unroll
    for (int mi = 0; mi < 4; ++mi) { a[mi][0] = rdA(cur, mi + 4, 0); a[mi][1] = rdA(cur, mi + 4, 1); }
    if (t + 2 < nt) QSTAGE_B(cur, t + 2);
    LGKM0();
    __builtin_amdgcn_s_setprio(1);
#pragma unroll
    for (int mi = 0; mi < 4; ++mi)
#pragma unroll
      for (int ni = 0; ni < 3; ++ni) {
        MFMA_ACC(acc[mi + 4][ni], a[mi][0], b[ni][0]);
        MFMA_ACC(acc[mi + 4][ni], a[mi][1], b[ni][1]);
      }
    __builtin_amdgcn_s_setprio(0);
    if (t + 1 < nt) {
      if (t + 2 < nt) {
        asm volatile("s_waitcnt vmcnt(3)" ::: "memory");
      } else {
        asm volatile("s_waitcnt vmcnt(0)" ::: "memory");
      }
    }
    BARRIER();
  }

#pragma unroll
  for (int ni = 0; ni < 3; ++ni) {
    int col = n0 + wc * 48 + ni * 16 + (lane & 15);
    float bv = bias[col];
#pragma unroll
    for (int mi = 0; mi < 8; ++mi) {
      int rbase = m0 + wr * 128 + mi * 16 + hig * 4;
#pragma unroll
      for (int r = 0; r < 4; ++r)
        Ch[(size_t)(rbase + r) * QKVN + col] = __float2bfloat16(acc[mi][ni][r] + bv);
    }
  }
#undef QSTAGE_A
#undef QSTAGE_B
}

// ---------------- Wo GEMM: 256x128 tile, full K, 256 blocks, 2-phase pipelined ----------------
// XCD column-strip swizzle: each XCD owns 4 bx x 8 by -> its B footprint = 4 MB (L2).
__global__ __launch_bounds__(512, 2) void wogemm_kernel(
    const bf16* __restrict__ A,   // [SEQ][HID]
    const bf16* __restrict__ Bt,  // [HID][HID]
    float* __restrict__ C) {      // [SEQ][HID]
  __shared__ bf16 lds[2][3][128 * 64];  // [buf][A0,A1,B]
  const int blk = blockIdx.x;
  const int xcd = blk & 7, loc = blk >> 3;
  const int n0 = (xcd * 4 + (loc & 3)) * 128;
  const int m0 = (loc >> 2) * 256;
  const int tid = threadIdx.x;
  const int lane = tid & 63;
  const int w = tid >> 6;
  const int wr = w >> 1, wc = w & 1;
  const int nt = HID / 64;

#define WSTAGE(buf, slot, t)                                                    \
  {                                                                             \
    const bf16* _s = ((slot) == 2) ? Bt : A;                                    \
    int _g0 = ((slot) == 2) ? n0 : (m0 + (slot) * 128);                         \
    _Pragma("unroll")                                                           \
    for (int _it = 0; _it < 2; ++_it) {                                         \
      int _row = w * 16 + _it * 8 + (lane >> 3);                                \
      int _ch = (lane & 7) ^ (_row & 7);                                        \
      gl_lds16(_s + (size_t)(_g0 + _row) * HID + (size_t)(t) * 64 + _ch * 8,    \
               &lds[buf][slot][(w * 16 + _it * 8) * 64]);                       \
    }                                                                           \
  }

  auto rdA = [&](int cur, int mi, int ks) {
    int rr = (wr & 1) * 64 + mi * 16 + (lane & 15);
    int byt = rr * 128 + (((ks * 32 + (lane >> 4) * 8) * 2) ^ ((rr & 7) << 4));
    return *reinterpret_cast<const bf16x8*>(
        reinterpret_cast<const char*>(&lds[cur][wr >> 1][0]) + byt);
  };
  auto rdB = [&](int cur, int ni, int ks) {
    int rr = wc * 64 + ni * 16 + (lane & 15);
    int byt = rr * 128 + (((ks * 32 + (lane >> 4) * 8) * 2) ^ ((rr & 7) << 4));
    return *reinterpret_cast<const bf16x8*>(
        reinterpret_cast<const char*>(&lds[cur][2][0]) + byt);
  };

  f32x4 acc[4][4];
  const f32x4 z = {0.f, 0.f, 0.f, 0.f};
#pragma unroll
  for (int i = 0; i < 4; ++i)
#pragma unroll
    for (int j = 0; j < 4; ++j) acc[i][j] = z;

  WSTAGE(0, 0, 0); WSTAGE(0, 1, 0); WSTAGE(0, 2, 0);
  WSTAGE(1, 2, 1);
  asm volatile("s_waitcnt vmcnt(2)" ::: "memory");
  BARRIER();

  bf16x8 a[2][2], b[4][2];
  int cur = 0;
  for (int t = 0; t < nt; ++t, cur ^= 1) {
#pragma unroll
    for (int mi = 0; mi < 2; ++mi) { a[mi][0] = rdA(cur, mi, 0); a[mi][1] = rdA(cur, mi, 1); }
#pragma unroll
    for (int ni = 0; ni < 4; ++ni) { b[ni][0] = rdB(cur, ni, 0); b[ni][1] = rdB(cur, ni, 1); }
    if (t + 1 < nt) { WSTAGE(cur ^ 1, 0, t + 1); WSTAGE(cur ^ 1, 1, t + 1); }
    LGKM0();
    __builtin_amdgcn_s_setprio(1);
#pragma unroll
    for (int mi = 0; mi < 2; ++mi)
#pragma unroll
      for (int ni = 0; ni < 4; ++ni) {
        MFMA_ACC(acc[mi][ni], a[mi][0], b[ni][0]);
        MFMA_ACC(acc[mi][ni], a[mi][1], b[ni][1]);
      }
    __builtin_amdgcn_s_setprio(0);
    BARRIER();
#pragma unroll
    for (int mi = 0; mi < 2; ++mi) { a[mi][0] = rdA(cur, mi + 2, 0); a[mi][1] = rdA(cur, mi + 2, 1); }
    if (t + 2 < nt) WSTAGE(cur, 2, t + 2);
    LGKM0();
    __builtin_amdgcn_s_setprio(1);
#pragma unroll
    for (int mi = 0; mi < 2; ++mi)
#pragma unroll
      for (int ni = 0; ni < 4; ++ni) {
        MFMA_ACC(acc[mi + 2][ni], a[mi][0], b[ni][0]);
        MFMA_ACC(acc[mi + 2][ni], a[mi][1], b[ni][1]);
      }
    __builtin_amdgcn_s_setprio(0);
    if (t + 1 < nt) {
      if (t + 2 < nt) {
        asm volatile("s_waitcnt vmcnt(2)" ::: "memory");
      } else {
        asm volatile("s_waitcnt vmcnt(0)" ::: "memory");
      }
    }
    BARRIER();
  }

#pragma unroll
  for (int ni = 0; ni < 4; ++ni) {
    int col = n0 + wc * 64 + ni * 16 + (lane & 15);
#pragma unroll
    for (int mi = 0; mi < 4; ++mi) {
      int rbase = m0 + wr * 64 + mi * 16 + (lane >> 4) * 4;
#pragma unroll
      for (int r = 0; r < 4; ++r)
        C[(size_t)(rbase + r) * HID + col] = acc[mi][ni][r];
    }
  }
#undef WSTAGE
}

// ---------------- flash attention: paired q-tiles (qb=pr and qb=31-pr), no split ----------------
__global__ __launch_bounds__(256) void attn_kernel(
    const bf16* __restrict__ Q, const bf16* __restrict__ Kb,
    const bf16* __restrict__ Vt, bf16* __restrict__ AO) {
  __shared__ bf16 Ks[64 * 128];
  __shared__ bf16 Vs[128 * 64];
  __shared__ bf16 Ps[4][16 * 64];
  const int tid = threadIdx.x, lane = tid & 63, w = tid >> 6;
  const int b = blockIdx.x;
  const int H = b & 31;
  const int pr = b >> 5;
  const int kvh = H >> 2;
  const int hig = lane >> 4;
  const int q_loc = lane & 15;
  const f32x4 z = {0.f, 0.f, 0.f, 0.f};

#pragma unroll
  for (int pass = 0; pass < 2; ++pass) {
    const int qb = pass ? (31 - pr) : pr;
    const int qw = qb * 64 + w * 16;
    const int qa = qw + q_loc;

    bf16x8 aq[4];
#pragma unroll
    for (int kd = 0; kd < 4; ++kd) {
      int row = qw + q_loc;
      int d = kd * 32 + hig * 8;
      aq[kd] = *reinterpret_cast<const bf16x8*>(Q + (size_t)row * HID + H * HD + d);
    }

    float m_run = -1e30f, l_run = 0.0f;
    f32x4 o[8];
#pragma unroll
    for (int dt = 0; dt < 8; ++dt) o[dt] = z;

    for (int t = 0; t <= qb; ++t) {
      int kvbase = t * 64;
#pragma unroll
      for (int it = 0; it < 4; ++it) {
        int c = w * 4 + it;
        int row = c * 4 + (lane >> 4);
        int sb = ((lane & 15) * 16) ^ ((row & 7) << 4);
        gl_lds16(Kb + (size_t)(kvbase + row) * KVDIM + kvh * HD + (sb >> 1), &Ks[c * 512]);
      }
#pragma unroll
      for (int it = 0; it < 4; ++it) {
        int c = w * 4 + it;
        int row = c * 8 + (lane >> 3);
        int sb = ((lane & 7) * 16) ^ ((row & 7) << 4);
        gl_lds16(Vt + (size_t)(kvh * HD + row) * SEQ + kvbase + (sb >> 1), &Vs[c * 512]);
      }
      __syncthreads();

      f32x4 sf[4];
#pragma unroll
      for (int j = 0; j < 4; ++j) sf[j] = z;
#pragma unroll
      for (int j = 0; j < 4; ++j) {
#pragma unroll
        for (int kd = 0; kd < 4; ++kd) {
          int r = j * 16 + q_loc;
          int byt = r * 256 + (((kd * 32 + hig * 8) * 2) ^ ((r & 7) << 4));
          bf16x8 kfr = *reinterpret_cast<const bf16x8*>(reinterpret_cast<const char*>(Ks) + byt);
          sf[j] = __builtin_amdgcn_mfma_f32_16x16x32_bf16(kfr, aq[kd], sf[j], 0, 0, 0);
        }
      }

      float vals[4][4];
      bool diag = (t == qb);
#pragma unroll
      for (int j = 0; j < 4; ++j)
#pragma unroll
        for (int r = 0; r < 4; ++r) {
          float v = sf[j][r];
          if (diag) {
            int ka = kvbase + j * 16 + hig * 4 + r;
            if (ka > qa) v = -1e30f;
          }
          vals[j][r] = v;
        }

      float m01 = fmaxf(fmaxf(vals[0][0], vals[0][1]), fmaxf(vals[0][2], vals[0][3]));
      float m23 = fmaxf(fmaxf(vals[1][0], vals[1][1]), fmaxf(vals[1][2], vals[1][3]));
      float m45 = fmaxf(fmaxf(vals[2][0], vals[2][1]), fmaxf(vals[2][2], vals[2][3]));
      float m67 = fmaxf(fmaxf(vals[3][0], vals[3][1]), fmaxf(vals[3][2], vals[3][3]));
      float m = fmaxf(fmaxf(m01, m23), fmaxf(m45, m67));
      m = fmaxf(m, __shfl_xor(m, 16));
      m = fmaxf(m, __shfl_xor(m, 32));
      float m_old = m_run;
      float mn = fmaxf(m_old, m);
      m_run = mn;
      float alpha = __builtin_exp2f(m_old - mn);

      float p[4][4];
      float rs = 0.0f;
#pragma unroll
      for (int j = 0; j < 4; ++j)
#pragma unroll
        for (int r = 0; r < 4; ++r) {
          p[j][r] = __builtin_exp2f(vals[j][r] - mn);
          rs += p[j][r];
        }
      rs += __shfl_xor(rs, 16);
      rs += __shfl_xor(rs, 32);
      l_run = l_run * alpha + rs;

#pragma unroll
      for (int j = 0; j < 4; ++j) {
        bf16 tmp[4] = {__float2bfloat16(p[j][0]), __float2bfloat16(p[j][1]),
                       __float2bfloat16(p[j][2]), __float2bfloat16(p[j][3])};
        int coff = (j * 16 + hig * 4) * 2;
        int byt = q_loc * 128 + (coff ^ ((q_loc & 7) << 4));
        *reinterpret_cast<uint2*>(reinterpret_cast<char*>(&Ps[w][0]) + byt) =
            *reinterpret_cast<const uint2*>(tmp);
      }

      if (__any(mn > m_old)) {
#pragma unroll
        for (int r = 0; r < 4; ++r) {
          float alr = __shfl(alpha, hig * 4 + r);
#pragma unroll
          for (int dt = 0; dt < 8; ++dt) o[dt][r] *= alr;
        }
      }

      bf16x8 pa[2];
#pragma unroll
      for (int ks = 0; ks < 2; ++ks) {
        int byt = q_loc * 128 + (((ks * 32 + hig * 8) * 2) ^ ((q_loc & 7) << 4));
        pa[ks] = *reinterpret_cast<const bf16x8*>(reinterpret_cast<const char*>(&Ps[w][0]) + byt);
      }
#pragma unroll
      for (int dt = 0; dt < 8; ++dt)
#pragma unroll
        for (int ks = 0; ks < 2; ++ks) {
          int vrow = dt * 16 + q_loc;
          int byt = vrow * 128 + (((ks * 32 + hig * 8) * 2) ^ ((vrow & 7) << 4));
          bf16x8 vb = *reinterpret_cast<const bf16x8*>(reinterpret_cast<const char*>(Vs) + byt);
          o[dt] = __builtin_amdgcn_mfma_f32_16x16x32_bf16(pa[ks], vb, o[dt], 0, 0, 0);
        }
      __syncthreads();
    }

#pragma unroll
    for (int r = 0; r < 4; ++r) {
      float li = __shfl(l_run, hig * 4 + r);
      float linv = 1.0f / li;
#pragma unroll
      for (int dt = 0; dt < 8; ++dt) {
        int qrow = qw + hig * 4 + r;
        int d = dt * 16 + q_loc;
        AO[(size_t)qrow * HID + H * HD + d] = __float2bfloat16(o[dt][r] * linv);
      }
    }
  }
}

extern "C" void kernel_launch(void* const* d_in, const int* in_sizes, int n_in,
                              void* d_out, int out_size, void* d_ws, size_t ws_size,
                              hipStream_t stream) {
  const float* hidden = (const float*)d_in[0];
  const float* Wq = (const float*)d_in[2];
  const float* bq = (const float*)d_in[3];
  const float* Wk = (const float*)d_in[4];
  const float* bk = (const float*)d_in[5];
  const float* Wv = (const float*)d_in[6];
  const float* bv = (const float*)d_in[7];
  const float* Wo = (const float*)d_in[8];
  float* out = (float*)d_out;

  // workspace map (144 MiB used):
  char* ws = (char*)d_ws;
  bf16*  Wqkvt  = (bf16*)(ws + (size_t)0 * MiB);    // 48 MiB  [Q|K|V]^T bf16
  bf16*  Xb     = (bf16*)(ws + (size_t)48 * MiB);   // 16 MiB
  bf16*  Cqkvh  = (bf16*)(ws + (size_t)64 * MiB);   // 24 MiB  bf16 QKV out [64,88)
  bf16*  Wot    = (bf16*)(ws + (size_t)88 * MiB);   // 32 MiB  [88,120)
  bf16*  Qb     = (bf16*)(ws + (size_t)120 * MiB);  // 16 MiB
  bf16*  Kb     = (bf16*)(ws + (size_t)136 * MiB);  // 4 MiB
  bf16*  Vt     = (bf16*)(ws + (size_t)140 * MiB);  // 4 MiB (ends 144)
  // stream-ordered aliases:
  float* bqkv   = (float*)Qb;                       // consumed by QKV GEMM, then rope overwrites
  bf16*  AO     = Cqkvh;                            // [64,80): Cqkvh dead after postqkv

  concat_bias_kernel<<<QKVN / 256, 256, 0, stream>>>(bq, bk, bv, bqkv);
  transpose_all_kernel<<<49152, dim3(32, 8), 0, stream>>>(
      Wq, Wk, Wv, Wo, Wqkvt, Wot, hidden, Xb);

  // QKV GEMM: 256x192 tiles, full K, 256 blocks, bf16 out
  qkvgemm_kernel<<<256, 512, 0, stream>>>(Xb, Wqkvt, bqkv, Cqkvh);

  // fused rope-Q (pre-scaled) / rope-K / V-transpose
  postqkv_kernel<<<12288, 256, 0, stream>>>(Cqkvh, Qb, Kb, Vt);

  // paired-q-tile attention: 512 blocks, exactly 33 tile-iters each
  attn_kernel<<<512, 256, 0, stream>>>(Qb, Kb, Vt, AO);

  // Wo GEMM: 256x128 tiles, full K, 256 blocks, fp32 direct to out
  wogemm_kernel<<<256, 512, 0, stream>>>(AO, Wot, out);
}

// Round 19
// 300.671 us; speedup vs baseline: 1.2026x; 1.0244x over previous
//
#include <hip/hip_runtime.h>
#include <hip/hip_bf16.h>

typedef __hip_bfloat16 bf16;
typedef __attribute__((ext_vector_type(8))) __bf16 bf16x8;
typedef __attribute__((ext_vector_type(4))) float f32x4;

#define SEQ 2048
#define HID 4096
#define NH 32
#define NKV 8
#define HD 128
#define KVDIM 1024
#define QKVN 6144

#define MiB (1024 * 1024)
// (1/sqrt(128)) * log2(e): folded into rope-Q so attention softmax runs in exp2 domain
#define SCALE_LOG2E 0.12751743f

__device__ __forceinline__ void gl_lds16(const void* g, void* lds) {
  __builtin_amdgcn_global_load_lds((const __attribute__((address_space(1))) void*)g,
                                   (__attribute__((address_space(3))) void*)lds,
                                   16, 0, 0);
}

__device__ __forceinline__ float unplo(unsigned u) { return __uint_as_float(u << 16); }
__device__ __forceinline__ float unphi(unsigned u) { return __uint_as_float(u & 0xffff0000u); }
__device__ __forceinline__ unsigned packbf(float a, float b) {
  bf16 t[2] = {__float2bfloat16(a), __float2bfloat16(b)};
  return *reinterpret_cast<unsigned*>(t);
}

// ---------------- merged weight transpose + hidden cvt + bias concat ----------------
// tiles: [0,16384) Wq, [16384,20480) Wk, [20480,24576) Wv, [24576,40960) Wo,
//        [40960,49152) hidden fp32->bf16, [49152,49176) bias concat
__global__ void transpose_all_kernel(const float* __restrict__ Wq, const float* __restrict__ Wk,
                                     const float* __restrict__ Wv, const float* __restrict__ Wo,
                                     bf16* __restrict__ Wqkvt, bf16* __restrict__ Wot,
                                     const float* __restrict__ hidden, bf16* __restrict__ Xb,
                                     const float* __restrict__ bq, const float* __restrict__ bk,
                                     const float* __restrict__ bv, float* __restrict__ bqkv) {
  __shared__ float tile[32][33];
  int t = blockIdx.x;
  if (t >= 49152) {
    int i = (t - 49152) * 256 + threadIdx.y * 32 + threadIdx.x;
    bqkv[i] = (i < HID) ? bq[i] : (i < HID + KVDIM ? bk[i - HID] : bv[i - HID - KVDIM]);
    return;
  }
  if (t >= 40960) {
    int i = ((t - 40960) * 256 + threadIdx.y * 32 + threadIdx.x) * 4;
    float4 v = *reinterpret_cast<const float4*>(hidden + i);
    bf16 o[4] = {__float2bfloat16(v.x), __float2bfloat16(v.y),
                 __float2bfloat16(v.z), __float2bfloat16(v.w)};
    *reinterpret_cast<short4*>(Xb + i) = *reinterpret_cast<const short4*>(o);
    return;
  }
  const float* in;
  bf16* out;
  int si, xt, yt;
  if (t < 16384)      { in = Wq; out = Wqkvt;                           si = HID;   xt = t & 127; yt = t >> 7; }
  else if (t < 20480) { t -= 16384; in = Wk; out = Wqkvt + (size_t)HID * HID;           si = KVDIM; xt = t & 31; yt = t >> 5; }
  else if (t < 24576) { t -= 20480; in = Wv; out = Wqkvt + (size_t)(HID + KVDIM) * HID; si = KVDIM; xt = t & 31; yt = t >> 5; }
  else                { t -= 24576; in = Wo; out = Wot;                 si = HID;   xt = t & 127; yt = t >> 7; }
  int c0 = xt * 32, r0 = yt * 32;
  int tx = threadIdx.x, ty = threadIdx.y;
#pragma unroll
  for (int i = 0; i < 32; i += 8)
    tile[ty + i][tx] = in[(size_t)(r0 + ty + i) * si + (c0 + tx)];
  __syncthreads();
#pragma unroll
  for (int i = 0; i < 32; i += 8)
    out[(size_t)(c0 + ty + i) * HID + (r0 + tx)] = __float2bfloat16(tile[tx][ty + i]);
}

// ---------------- fused post-QKV: rope Q (pre-scaled), rope K, V transpose ----------------
__global__ void postqkv_kernel(const bf16* __restrict__ Ch, bf16* __restrict__ Qb,
                               bf16* __restrict__ Kb, bf16* __restrict__ Vt) {
  __shared__ float tile[32][33];
  int b = blockIdx.x;
  int tid = threadIdx.x;
  if (b < 10240) {
    bool isQ = (b < 8192);
    int idx = (isQ ? b : b - 8192) * 256 + tid;
    int j = idx & 31;
    int h = (idx >> 5) & (isQ ? 31 : 7);
    int s = idx >> (isQ ? 10 : 8);
    size_t bi = (size_t)s * QKVN + (isQ ? 0 : HID) + h * HD;
    unsigned u1 = *reinterpret_cast<const unsigned*>(Ch + bi + 2 * j);
    unsigned u2 = *reinterpret_cast<const unsigned*>(Ch + bi + 64 + 2 * j);
    float x1a = unplo(u1), x1b = unphi(u1);
    float x2a = unplo(u2), x2b = unphi(u2);
    float inv0 = __expf(-(float)(2 * j) * 0.14391156831212787f);
    float inv1 = __expf(-(float)(2 * j + 1) * 0.14391156831212787f);
    float sn0, cs0, sn1, cs1;
    __sincosf((float)s * inv0, &sn0, &cs0);
    __sincosf((float)s * inv1, &sn1, &cs1);
    if (isQ) {
      cs0 *= SCALE_LOG2E; sn0 *= SCALE_LOG2E;
      cs1 *= SCALE_LOG2E; sn1 *= SCALE_LOG2E;
    }
    size_t bo = (size_t)s * (isQ ? HID : KVDIM) + h * HD;
    bf16* Ob = isQ ? Qb : Kb;
    *reinterpret_cast<unsigned*>(Ob + bo + 2 * j) =
        packbf(x1a * cs0 - x2a * sn0, x1b * cs1 - x2b * sn1);
    *reinterpret_cast<unsigned*>(Ob + bo + 64 + 2 * j) =
        packbf(x2a * cs0 + x1a * sn0, x2b * cs1 + x1b * sn1);
  } else {
    int t = b - 10240;
    int xt = t & 31, yt = t >> 5;
    int tx = tid & 31, ty = tid >> 5;
#pragma unroll
    for (int i = 0; i < 32; i += 8)
      tile[ty + i][tx] = __bfloat162float(Ch[(size_t)(yt * 32 + ty + i) * QKVN + (HID + KVDIM) + xt * 32 + tx]);
    __syncthreads();
#pragma unroll
    for (int i = 0; i < 32; i += 8)
      Vt[(size_t)(xt * 32 + ty + i) * SEQ + (yt * 32 + tx)] = __float2bfloat16(tile[tx][ty + i]);
  }
}

#define BARRIER() __builtin_amdgcn_s_barrier()
#define MFMA_ACC(d, x, y) d = __builtin_amdgcn_mfma_f32_16x16x32_bf16(x, y, d, 0, 0, 0)

// ---------------- QKV GEMM: 256x192 tile, full K, 256 blocks, 2-phase pipelined ----------------
// XCD column-strip swizzle. Plain ds_reads: compiler emits fine-grained lgkmcnt
// before each dependent MFMA (no forced full drain).
__global__ __launch_bounds__(512, 2) void qkvgemm_kernel(
    const bf16* __restrict__ A,   // [SEQ][HID]
    const bf16* __restrict__ Bt,  // [QKVN][HID]
    const float* __restrict__ bias,
    bf16* __restrict__ Ch) {      // [SEQ][QKVN]
  __shared__ bf16 lds[2][448 * 64];  // A rows [0,256), B rows [256,448)
  const int blk = blockIdx.x;
  const int xcd = blk & 7, loc = blk >> 3;
  const int bx = xcd * 4 + (loc & 3);   // [0,32)
  const int by = loc >> 2;              // [0,8)
  const int n0 = bx * 192;
  const int m0 = by * 256;
  const int tid = threadIdx.x;
  const int lane = tid & 63;
  const int w = tid >> 6;
  const int wr = w >> 2, wc = w & 3;            // 2M x 4N
  const int hig = lane >> 4;
  const int nt = HID / 64;                       // 64

#define QSTAGE_A(buf, t)                                                          \
  {                                                                               \
    _Pragma("unroll")                                                             \
    for (int _c = 0; _c < 4; ++_c) {                                              \
      int _row = _c * 64 + w * 8 + (lane >> 3);                                   \
      int _ch = (lane & 7) ^ ((lane >> 3) & 7);                                   \
      gl_lds16(A + (size_t)(m0 + _row) * HID + (size_t)(t) * 64 + _ch * 8,        \
               &lds[buf][(_c * 64 + w * 8) * 64]);                                \
    }                                                                             \
  }
#define QSTAGE_B(buf, t)                                                          \
  {                                                                               \
    _Pragma("unroll")                                                             \
    for (int _c = 0; _c < 3; ++_c) {                                              \
      int _row = _c * 64 + w * 8 + (lane >> 3);                                   \
      int _ch = (lane & 7) ^ ((lane >> 3) & 7);                                   \
      gl_lds16(Bt + (size_t)(n0 + _row) * HID + (size_t)(t) * 64 + _ch * 8,       \
               &lds[buf][(256 + _c * 64 + w * 8) * 64]);                          \
    }                                                                             \
  }

  auto rdA = [&](int cur, int mi, int ks) {
    int rr = wr * 128 + mi * 16 + (lane & 15);
    int byt = rr * 128 + (((ks * 32 + hig * 8) * 2) ^ ((rr & 7) << 4));
    return *reinterpret_cast<const bf16x8*>(
        reinterpret_cast<const char*>(&lds[cur][0]) + byt);
  };
  auto rdB = [&](int cur, int ni, int ks) {
    int rr = wc * 48 + ni * 16 + (lane & 15);
    int byt = 32768 + rr * 128 + (((ks * 32 + hig * 8) * 2) ^ ((rr & 7) << 4));
    return *reinterpret_cast<const bf16x8*>(
        reinterpret_cast<const char*>(&lds[cur][0]) + byt);
  };

  f32x4 acc[8][3];
  const f32x4 z = {0.f, 0.f, 0.f, 0.f};
#pragma unroll
  for (int i = 0; i < 8; ++i)
#pragma unroll
    for (int j = 0; j < 3; ++j) acc[i][j] = z;

  QSTAGE_A(0, 0); QSTAGE_B(0, 0);
  QSTAGE_B(1, 1);
  asm volatile("s_waitcnt vmcnt(3)" ::: "memory");
  BARRIER();

  bf16x8 a[4][2], b[3][2];
  int cur = 0;
  for (int t = 0; t < nt; ++t, cur ^= 1) {
#pragma unroll
    for (int mi = 0; mi < 4; ++mi) { a[mi][0] = rdA(cur, mi, 0); a[mi][1] = rdA(cur, mi, 1); }
#pragma unroll
    for (int ni = 0; ni < 3; ++ni) { b[ni][0] = rdB(cur, ni, 0); b[ni][1] = rdB(cur, ni, 1); }
    if (t + 1 < nt) QSTAGE_A(cur ^ 1, t + 1);
    __builtin_amdgcn_s_setprio(1);
#pragma unroll
    for (int mi = 0; mi < 4; ++mi)
#pragma unroll
      for (int ni = 0; ni < 3; ++ni) {
        MFMA_ACC(acc[mi][ni], a[mi][0], b[ni][0]);
        MFMA_ACC(acc[mi][ni], a[mi][1], b[ni][1]);
      }
    __builtin_amdgcn_s_setprio(0);
    BARRIER();
#pragma unroll
    for (int mi = 0; mi < 4; ++mi) { a[mi][0] = rdA(cur, mi + 4, 0); a[mi][1] = rdA(cur, mi + 4, 1); }
    if (t + 2 < nt) QSTAGE_B(cur, t + 2);
    __builtin_amdgcn_s_setprio(1);
#pragma unroll
    for (int mi = 0; mi < 4; ++mi)
#pragma unroll
      for (int ni = 0; ni < 3; ++ni) {
        MFMA_ACC(acc[mi + 4][ni], a[mi][0], b[ni][0]);
        MFMA_ACC(acc[mi + 4][ni], a[mi][1], b[ni][1]);
      }
    __builtin_amdgcn_s_setprio(0);
    if (t + 1 < nt) {
      if (t + 2 < nt) {
        asm volatile("s_waitcnt vmcnt(3)" ::: "memory");
      } else {
        asm volatile("s_waitcnt vmcnt(0)" ::: "memory");
      }
    }
    BARRIER();
  }

#pragma unroll
  for (int ni = 0; ni < 3; ++ni) {
    int col = n0 + wc * 48 + ni * 16 + (lane & 15);
    float bv = bias[col];
#pragma unroll
    for (int mi = 0; mi < 8; ++mi) {
      int rbase = m0 + wr * 128 + mi * 16 + hig * 4;
#pragma unroll
      for (int r = 0; r < 4; ++r)
        Ch[(size_t)(rbase + r) * QKVN + col] = __float2bfloat16(acc[mi][ni][r] + bv);
    }
  }
#undef QSTAGE_A
#undef QSTAGE_B
}

// ---------------- Wo GEMM: 256x128 tile, full K, 256 blocks, 2-phase pipelined ----------------
__global__ __launch_bounds__(512, 2) void wogemm_kernel(
    const bf16* __restrict__ A,   // [SEQ][HID]
    const bf16* __restrict__ Bt,  // [HID][HID]
    float* __restrict__ C) {      // [SEQ][HID]
  __shared__ bf16 lds[2][3][128 * 64];  // [buf][A0,A1,B]
  const int blk = blockIdx.x;
  const int xcd = blk & 7, loc = blk >> 3;
  const int n0 = (xcd * 4 + (loc & 3)) * 128;
  const int m0 = (loc >> 2) * 256;
  const int tid = threadIdx.x;
  const int lane = tid & 63;
  const int w = tid >> 6;
  const int wr = w >> 1, wc = w & 1;
  const int nt = HID / 64;

#define WSTAGE(buf, slot, t)                                                    \
  {                                                                             \
    const bf16* _s = ((slot) == 2) ? Bt : A;                                    \
    int _g0 = ((slot) == 2) ? n0 : (m0 + (slot) * 128);                         \
    _Pragma("unroll")                                                           \
    for (int _it = 0; _it < 2; ++_it) {                                         \
      int _row = w * 16 + _it * 8 + (lane >> 3);                                \
      int _ch = (lane & 7) ^ (_row & 7);                                        \
      gl_lds16(_s + (size_t)(_g0 + _row) * HID + (size_t)(t) * 64 + _ch * 8,    \
               &lds[buf][slot][(w * 16 + _it * 8) * 64]);                       \
    }                                                                           \
  }

  auto rdA = [&](int cur, int mi, int ks) {
    int rr = (wr & 1) * 64 + mi * 16 + (lane & 15);
    int byt = rr * 128 + (((ks * 32 + (lane >> 4) * 8) * 2) ^ ((rr & 7) << 4));
    return *reinterpret_cast<const bf16x8*>(
        reinterpret_cast<const char*>(&lds[cur][wr >> 1][0]) + byt);
  };
  auto rdB = [&](int cur, int ni, int ks) {
    int rr = wc * 64 + ni * 16 + (lane & 15);
    int byt = rr * 128 + (((ks * 32 + (lane >> 4) * 8) * 2) ^ ((rr & 7) << 4));
    return *reinterpret_cast<const bf16x8*>(
        reinterpret_cast<const char*>(&lds[cur][2][0]) + byt);
  };

  f32x4 acc[4][4];
  const f32x4 z = {0.f, 0.f, 0.f, 0.f};
#pragma unroll
  for (int i = 0; i < 4; ++i)
#pragma unroll
    for (int j = 0; j < 4; ++j) acc[i][j] = z;

  WSTAGE(0, 0, 0); WSTAGE(0, 1, 0); WSTAGE(0, 2, 0);
  WSTAGE(1, 2, 1);
  asm volatile("s_waitcnt vmcnt(2)" ::: "memory");
  BARRIER();

  bf16x8 a[2][2], b[4][2];
  int cur = 0;
  for (int t = 0; t < nt; ++t, cur ^= 1) {
#pragma unroll
    for (int mi = 0; mi < 2; ++mi) { a[mi][0] = rdA(cur, mi, 0); a[mi][1] = rdA(cur, mi, 1); }
#pragma unroll
    for (int ni = 0; ni < 4; ++ni) { b[ni][0] = rdB(cur, ni, 0); b[ni][1] = rdB(cur, ni, 1); }
    if (t + 1 < nt) { WSTAGE(cur ^ 1, 0, t + 1); WSTAGE(cur ^ 1, 1, t + 1); }
    __builtin_amdgcn_s_setprio(1);
#pragma unroll
    for (int mi = 0; mi < 2; ++mi)
#pragma unroll
      for (int ni = 0; ni < 4; ++ni) {
        MFMA_ACC(acc[mi][ni], a[mi][0], b[ni][0]);
        MFMA_ACC(acc[mi][ni], a[mi][1], b[ni][1]);
      }
    __builtin_amdgcn_s_setprio(0);
    BARRIER();
#pragma unroll
    for (int mi = 0; mi < 2; ++mi) { a[mi][0] = rdA(cur, mi + 2, 0); a[mi][1] = rdA(cur, mi + 2, 1); }
    if (t + 2 < nt) WSTAGE(cur, 2, t + 2);
    __builtin_amdgcn_s_setprio(1);
#pragma unroll
    for (int mi = 0; mi < 2; ++mi)
#pragma unroll
      for (int ni = 0; ni < 4; ++ni) {
        MFMA_ACC(acc[mi + 2][ni], a[mi][0], b[ni][0]);
        MFMA_ACC(acc[mi + 2][ni], a[mi][1], b[ni][1]);
      }
    __builtin_amdgcn_s_setprio(0);
    if (t + 1 < nt) {
      if (t + 2 < nt) {
        asm volatile("s_waitcnt vmcnt(2)" ::: "memory");
      } else {
        asm volatile("s_waitcnt vmcnt(0)" ::: "memory");
      }
    }
    BARRIER();
  }

#pragma unroll
  for (int ni = 0; ni < 4; ++ni) {
    int col = n0 + wc * 64 + ni * 16 + (lane & 15);
#pragma unroll
    for (int mi = 0; mi < 4; ++mi) {
      int rbase = m0 + wr * 64 + mi * 16 + (lane >> 4) * 4;
#pragma unroll
      for (int r = 0; r < 4; ++r)
        C[(size_t)(rbase + r) * HID + col] = acc[mi][ni][r];
    }
  }
#undef WSTAGE
}

// ---------------- flash attention: paired q-tiles (qb=pr and qb=31-pr) ----------------
__global__ __launch_bounds__(256) void attn_kernel(
    const bf16* __restrict__ Q, const bf16* __restrict__ Kb,
    const bf16* __restrict__ Vt, bf16* __restrict__ AO) {
  __shared__ bf16 Ks[64 * 128];
  __shared__ bf16 Vs[128 * 64];
  __shared__ bf16 Ps[4][16 * 64];
  const int tid = threadIdx.x, lane = tid & 63, w = tid >> 6;
  const int b = blockIdx.x;
  const int H = b & 31;
  const int pr = b >> 5;
  const int kvh = H >> 2;
  const int hig = lane >> 4;
  const int q_loc = lane & 15;
  const f32x4 z = {0.f, 0.f, 0.f, 0.f};

#pragma unroll
  for (int pass = 0; pass < 2; ++pass) {
    const int qb = pass ? (31 - pr) : pr;
    const int qw = qb * 64 + w * 16;
    const int qa = qw + q_loc;

    bf16x8 aq[4];
#pragma unroll
    for (int kd = 0; kd < 4; ++kd) {
      int row = qw + q_loc;
      int d = kd * 32 + hig * 8;
      aq[kd] = *reinterpret_cast<const bf16x8*>(Q + (size_t)row * HID + H * HD + d);
    }

    float m_run = -1e30f, l_run = 0.0f;
    f32x4 o[8];
#pragma unroll
    for (int dt = 0; dt < 8; ++dt) o[dt] = z;

    for (int t = 0; t <= qb; ++t) {
      int kvbase = t * 64;
#pragma unroll
      for (int it = 0; it < 4; ++it) {
        int c = w * 4 + it;
        int row = c * 4 + (lane >> 4);
        int sb = ((lane & 15) * 16) ^ ((row & 7) << 4);
        gl_lds16(Kb + (size_t)(kvbase + row) * KVDIM + kvh * HD + (sb >> 1), &Ks[c * 512]);
      }
#pragma unroll
      for (int it = 0; it < 4; ++it) {
        int c = w * 4 + it;
        int row = c * 8 + (lane >> 3);
        int sb = ((lane & 7) * 16) ^ ((row & 7) << 4);
        gl_lds16(Vt + (size_t)(kvh * HD + row) * SEQ + kvbase + (sb >> 1), &Vs[c * 512]);
      }
      __syncthreads();

      f32x4 sf[4];
#pragma unroll
      for (int j = 0; j < 4; ++j) sf[j] = z;
#pragma unroll
      for (int j = 0; j < 4; ++j) {
#pragma unroll
        for (int kd = 0; kd < 4; ++kd) {
          int r = j * 16 + q_loc;
          int byt = r * 256 + (((kd * 32 + hig * 8) * 2) ^ ((r & 7) << 4));
          bf16x8 kfr = *reinterpret_cast<const bf16x8*>(reinterpret_cast<const char*>(Ks) + byt);
          sf[j] = __builtin_amdgcn_mfma_f32_16x16x32_bf16(kfr, aq[kd], sf[j], 0, 0, 0);
        }
      }

      float vals[4][4];
      bool diag = (t == qb);
#pragma unroll
      for (int j = 0; j < 4; ++j)
#pragma unroll
        for (int r = 0; r < 4; ++r) {
          float v = sf[j][r];
          if (diag) {
            int ka = kvbase + j * 16 + hig * 4 + r;
            if (ka > qa) v = -1e30f;
          }
          vals[j][r] = v;
        }

      float m01 = fmaxf(fmaxf(vals[0][0], vals[0][1]), fmaxf(vals[0][2], vals[0][3]));
      float m23 = fmaxf(fmaxf(vals[1][0], vals[1][1]), fmaxf(vals[1][2], vals[1][3]));
      float m45 = fmaxf(fmaxf(vals[2][0], vals[2][1]), fmaxf(vals[2][2], vals[2][3]));
      float m67 = fmaxf(fmaxf(vals[3][0], vals[3][1]), fmaxf(vals[3][2], vals[3][3]));
      float m = fmaxf(fmaxf(m01, m23), fmaxf(m45, m67));
      m = fmaxf(m, __shfl_xor(m, 16));
      m = fmaxf(m, __shfl_xor(m, 32));
      float m_old = m_run;
      float mn = fmaxf(m_old, m);
      m_run = mn;
      float alpha = __builtin_exp2f(m_old - mn);

      float p[4][4];
      float rs = 0.0f;
#pragma unroll
      for (int j = 0; j < 4; ++j)
#pragma unroll
        for (int r = 0; r < 4; ++r) {
          p[j][r] = __builtin_exp2f(vals[j][r] - mn);
          rs += p[j][r];
        }
      rs += __shfl_xor(rs, 16);
      rs += __shfl_xor(rs, 32);
      l_run = l_run * alpha + rs;

#pragma unroll
      for (int j = 0; j < 4; ++j) {
        bf16 tmp[4] = {__float2bfloat16(p[j][0]), __float2bfloat16(p[j][1]),
                       __float2bfloat16(p[j][2]), __float2bfloat16(p[j][3])};
        int coff = (j * 16 + hig * 4) * 2;
        int byt = q_loc * 128 + (coff ^ ((q_loc & 7) << 4));
        *reinterpret_cast<uint2*>(reinterpret_cast<char*>(&Ps[w][0]) + byt) =
            *reinterpret_cast<const uint2*>(tmp);
      }

      if (__any(mn > m_old)) {
#pragma unroll
        for (int r = 0; r < 4; ++r) {
          float alr = __shfl(alpha, hig * 4 + r);
#pragma unroll
          for (int dt = 0; dt < 8; ++dt) o[dt][r] *= alr;
        }
      }

      bf16x8 pa[2];
#pragma unroll
      for (int ks = 0; ks < 2; ++ks) {
        int byt = q_loc * 128 + (((ks * 32 + hig * 8) * 2) ^ ((q_loc & 7) << 4));
        pa[ks] = *reinterpret_cast<const bf16x8*>(reinterpret_cast<const char*>(&Ps[w][0]) + byt);
      }
#pragma unroll
      for (int dt = 0; dt < 8; ++dt)
#pragma unroll
        for (int ks = 0; ks < 2; ++ks) {
          int vrow = dt * 16 + q_loc;
          int byt = vrow * 128 + (((ks * 32 + hig * 8) * 2) ^ ((vrow & 7) << 4));
          bf16x8 vb = *reinterpret_cast<const bf16x8*>(reinterpret_cast<const char*>(Vs) + byt);
          o[dt] = __builtin_amdgcn_mfma_f32_16x16x32_bf16(pa[ks], vb, o[dt], 0, 0, 0);
        }
      __syncthreads();
    }

#pragma unroll
    for (int r = 0; r < 4; ++r) {
      float li = __shfl(l_run, hig * 4 + r);
      float linv = 1.0f / li;
#pragma unroll
      for (int dt = 0; dt < 8; ++dt) {
        int qrow = qw + hig * 4 + r;
        int d = dt * 16 + q_loc;
        AO[(size_t)qrow * HID + H * HD + d] = __float2bfloat16(o[dt][r] * linv);
      }
    }
  }
}

extern "C" void kernel_launch(void* const* d_in, const int* in_sizes, int n_in,
                              void* d_out, int out_size, void* d_ws, size_t ws_size,
                              hipStream_t stream) {
  const float* hidden = (const float*)d_in[0];
  const float* Wq = (const float*)d_in[2];
  const float* bq = (const float*)d_in[3];
  const float* Wk = (const float*)d_in[4];
  const float* bk = (const float*)d_in[5];
  const float* Wv = (const float*)d_in[6];
  const float* bv = (const float*)d_in[7];
  const float* Wo = (const float*)d_in[8];
  float* out = (float*)d_out;

  // workspace map (144 MiB used):
  char* ws = (char*)d_ws;
  bf16*  Wqkvt  = (bf16*)(ws + (size_t)0 * MiB);    // 48 MiB  [Q|K|V]^T bf16
  bf16*  Xb     = (bf16*)(ws + (size_t)48 * MiB);   // 16 MiB
  bf16*  Cqkvh  = (bf16*)(ws + (size_t)64 * MiB);   // 24 MiB  bf16 QKV out [64,88)
  bf16*  Wot    = (bf16*)(ws + (size_t)88 * MiB);   // 32 MiB  [88,120)
  bf16*  Qb     = (bf16*)(ws + (size_t)120 * MiB);  // 16 MiB
  bf16*  Kb     = (bf16*)(ws + (size_t)136 * MiB);  // 4 MiB
  bf16*  Vt     = (bf16*)(ws + (size_t)140 * MiB);  // 4 MiB (ends 144)
  // stream-ordered aliases:
  float* bqkv   = (float*)Qb;                       // consumed by QKV GEMM, then rope overwrites
  bf16*  AO     = Cqkvh;                            // [64,80): Cqkvh dead after postqkv

  transpose_all_kernel<<<49176, dim3(32, 8), 0, stream>>>(
      Wq, Wk, Wv, Wo, Wqkvt, Wot, hidden, Xb, bq, bk, bv, bqkv);

  // QKV GEMM: 256x192 tiles, full K, 256 blocks, bf16 out
  qkvgemm_kernel<<<256, 512, 0, stream>>>(Xb, Wqkvt, bqkv, Cqkvh);

  // fused rope-Q (pre-scaled) / rope-K / V-transpose
  postqkv_kernel<<<12288, 256, 0, stream>>>(Cqkvh, Qb, Kb, Vt);

  // paired-q-tile attention: 512 blocks, exactly 33 tile-iters each
  attn_kernel<<<512, 256, 0, stream>>>(Qb, Kb, Vt, AO);

  // Wo GEMM: 256x128 tiles, full K, 256 blocks, fp32 direct to out
  wogemm_kernel<<<256, 512, 0, stream>>>(AO, Wot, out);
}

// Round 20
// 296.672 us; speedup vs baseline: 1.2188x; 1.0135x over previous
//
#include <hip/hip_runtime.h>
#include <hip/hip_bf16.h>

typedef __hip_bfloat16 bf16;
typedef __attribute__((ext_vector_type(8))) __bf16 bf16x8;
typedef __attribute__((ext_vector_type(4))) float f32x4;

#define SEQ 2048
#define HID 4096
#define NH 32
#define NKV 8
#define HD 128
#define KVDIM 1024
#define QKVN 6144

#define MiB (1024 * 1024)
// (1/sqrt(128)) * log2(e): folded into rope-Q so attention softmax runs in exp2 domain
#define SCALE_LOG2E 0.12751743f

__device__ __forceinline__ void gl_lds16(const void* g, void* lds) {
  __builtin_amdgcn_global_load_lds((const __attribute__((address_space(1))) void*)g,
                                   (__attribute__((address_space(3))) void*)lds,
                                   16, 0, 0);
}

__device__ __forceinline__ float unplo(unsigned u) { return __uint_as_float(u << 16); }
__device__ __forceinline__ float unphi(unsigned u) { return __uint_as_float(u & 0xffff0000u); }
__device__ __forceinline__ unsigned packbf(float a, float b) {
  bf16 t[2] = {__float2bfloat16(a), __float2bfloat16(b)};
  return *reinterpret_cast<unsigned*>(t);
}

// ---------------- merged 64x64 weight transpose + hidden cvt + bias concat ----------------
// blocks: [0,4096) Wq, [4096,5120) Wk, [5120,6144) Wv, [6144,10240) Wo (64x64 tiles),
//         [10240,18432) hidden fp32->bf16, [18432,18456) bias concat. dim3(64,4).
__global__ void transpose_all_kernel(const float* __restrict__ Wq, const float* __restrict__ Wk,
                                     const float* __restrict__ Wv, const float* __restrict__ Wo,
                                     bf16* __restrict__ Wqkvt, bf16* __restrict__ Wot,
                                     const float* __restrict__ hidden, bf16* __restrict__ Xb,
                                     const float* __restrict__ bq, const float* __restrict__ bk,
                                     const float* __restrict__ bv, float* __restrict__ bqkv) {
  __shared__ float tile[64][65];
  int t = blockIdx.x;
  int tx = threadIdx.x, ty = threadIdx.y;
  int tid = ty * 64 + tx;
  if (t >= 18432) {
    int i = (t - 18432) * 256 + tid;
    bqkv[i] = (i < HID) ? bq[i] : (i < HID + KVDIM ? bk[i - HID] : bv[i - HID - KVDIM]);
    return;
  }
  if (t >= 10240) {
    int i = ((t - 10240) * 256 + tid) * 4;
    float4 v = *reinterpret_cast<const float4*>(hidden + i);
    bf16 o[4] = {__float2bfloat16(v.x), __float2bfloat16(v.y),
                 __float2bfloat16(v.z), __float2bfloat16(v.w)};
    *reinterpret_cast<short4*>(Xb + i) = *reinterpret_cast<const short4*>(o);
    return;
  }
  const float* in;
  bf16* out;
  int si, xt, yt;
  if (t < 4096)      { in = Wq; out = Wqkvt;                           si = HID;   xt = t & 63; yt = t >> 6; }
  else if (t < 5120) { t -= 4096; in = Wk; out = Wqkvt + (size_t)HID * HID;           si = KVDIM; xt = t & 15; yt = t >> 4; }
  else if (t < 6144) { t -= 5120; in = Wv; out = Wqkvt + (size_t)(HID + KVDIM) * HID; si = KVDIM; xt = t & 15; yt = t >> 4; }
  else               { t -= 6144; in = Wo; out = Wot;                 si = HID;   xt = t & 63; yt = t >> 6; }
  int c0 = xt * 64, r0 = yt * 64;
#pragma unroll
  for (int i = 0; i < 64; i += 4)
    tile[ty + i][tx] = in[(size_t)(r0 + ty + i) * si + (c0 + tx)];
  __syncthreads();
#pragma unroll
  for (int i = 0; i < 64; i += 4)
    out[(size_t)(c0 + ty + i) * HID + (r0 + tx)] = __float2bfloat16(tile[tx][ty + i]);
}

// ---------------- fused post-QKV: rope Q (pre-scaled), rope K, V transpose ----------------
__global__ void postqkv_kernel(const bf16* __restrict__ Ch, bf16* __restrict__ Qb,
                               bf16* __restrict__ Kb, bf16* __restrict__ Vt) {
  __shared__ float tile[32][33];
  int b = blockIdx.x;
  int tid = threadIdx.x;
  if (b < 10240) {
    bool isQ = (b < 8192);
    int idx = (isQ ? b : b - 8192) * 256 + tid;
    int j = idx & 31;
    int h = (idx >> 5) & (isQ ? 31 : 7);
    int s = idx >> (isQ ? 10 : 8);
    size_t bi = (size_t)s * QKVN + (isQ ? 0 : HID) + h * HD;
    unsigned u1 = *reinterpret_cast<const unsigned*>(Ch + bi + 2 * j);
    unsigned u2 = *reinterpret_cast<const unsigned*>(Ch + bi + 64 + 2 * j);
    float x1a = unplo(u1), x1b = unphi(u1);
    float x2a = unplo(u2), x2b = unphi(u2);
    float inv0 = __expf(-(float)(2 * j) * 0.14391156831212787f);
    float inv1 = __expf(-(float)(2 * j + 1) * 0.14391156831212787f);
    float sn0, cs0, sn1, cs1;
    __sincosf((float)s * inv0, &sn0, &cs0);
    __sincosf((float)s * inv1, &sn1, &cs1);
    if (isQ) {
      cs0 *= SCALE_LOG2E; sn0 *= SCALE_LOG2E;
      cs1 *= SCALE_LOG2E; sn1 *= SCALE_LOG2E;
    }
    size_t bo = (size_t)s * (isQ ? HID : KVDIM) + h * HD;
    bf16* Ob = isQ ? Qb : Kb;
    *reinterpret_cast<unsigned*>(Ob + bo + 2 * j) =
        packbf(x1a * cs0 - x2a * sn0, x1b * cs1 - x2b * sn1);
    *reinterpret_cast<unsigned*>(Ob + bo + 64 + 2 * j) =
        packbf(x2a * cs0 + x1a * sn0, x2b * cs1 + x1b * sn1);
  } else {
    int t = b - 10240;
    int xt = t & 31, yt = t >> 5;
    int tx = tid & 31, ty = tid >> 5;
#pragma unroll
    for (int i = 0; i < 32; i += 8)
      tile[ty + i][tx] = __bfloat162float(Ch[(size_t)(yt * 32 + ty + i) * QKVN + (HID + KVDIM) + xt * 32 + tx]);
    __syncthreads();
#pragma unroll
    for (int i = 0; i < 32; i += 8)
      Vt[(size_t)(xt * 32 + ty + i) * SEQ + (yt * 32 + tx)] = __float2bfloat16(tile[tx][ty + i]);
  }
}

#define BARRIER() __builtin_amdgcn_s_barrier()
#define MFMA_ACC(d, x, y) d = __builtin_amdgcn_mfma_f32_16x16x32_bf16(x, y, d, 0, 0, 0)

// ---------------- QKV GEMM: 256x192 tile, full K, 256 blocks, 2-phase pipelined ----------------
__global__ __launch_bounds__(512, 2) void qkvgemm_kernel(
    const bf16* __restrict__ A,   // [SEQ][HID]
    const bf16* __restrict__ Bt,  // [QKVN][HID]
    const float* __restrict__ bias,
    bf16* __restrict__ Ch) {      // [SEQ][QKVN]
  __shared__ bf16 lds[2][448 * 64];  // A rows [0,256), B rows [256,448)
  const int blk = blockIdx.x;
  const int xcd = blk & 7, loc = blk >> 3;
  const int bx = xcd * 4 + (loc & 3);   // [0,32)
  const int by = loc >> 2;              // [0,8)
  const int n0 = bx * 192;
  const int m0 = by * 256;
  const int tid = threadIdx.x;
  const int lane = tid & 63;
  const int w = tid >> 6;
  const int wr = w >> 2, wc = w & 3;            // 2M x 4N
  const int hig = lane >> 4;
  const int nt = HID / 64;                       // 64

#define QSTAGE_A(buf, t)                                                          \
  {                                                                               \
    _Pragma("unroll")                                                             \
    for (int _c = 0; _c < 4; ++_c) {                                              \
      int _row = _c * 64 + w * 8 + (lane >> 3);                                   \
      int _ch = (lane & 7) ^ ((lane >> 3) & 7);                                   \
      gl_lds16(A + (size_t)(m0 + _row) * HID + (size_t)(t) * 64 + _ch * 8,        \
               &lds[buf][(_c * 64 + w * 8) * 64]);                                \
    }                                                                             \
  }
#define QSTAGE_B(buf, t)                                                          \
  {                                                                               \
    _Pragma("unroll")                                                             \
    for (int _c = 0; _c < 3; ++_c) {                                              \
      int _row = _c * 64 + w * 8 + (lane >> 3);                                   \
      int _ch = (lane & 7) ^ ((lane >> 3) & 7);                                   \
      gl_lds16(Bt + (size_t)(n0 + _row) * HID + (size_t)(t) * 64 + _ch * 8,       \
               &lds[buf][(256 + _c * 64 + w * 8) * 64]);                          \
    }                                                                             \
  }

  auto rdA = [&](int cur, int mi, int ks) {
    int rr = wr * 128 + mi * 16 + (lane & 15);
    int byt = rr * 128 + (((ks * 32 + hig * 8) * 2) ^ ((rr & 7) << 4));
    return *reinterpret_cast<const bf16x8*>(
        reinterpret_cast<const char*>(&lds[cur][0]) + byt);
  };
  auto rdB = [&](int cur, int ni, int ks) {
    int rr = wc * 48 + ni * 16 + (lane & 15);
    int byt = 32768 + rr * 128 + (((ks * 32 + hig * 8) * 2) ^ ((rr & 7) << 4));
    return *reinterpret_cast<const bf16x8*>(
        reinterpret_cast<const char*>(&lds[cur][0]) + byt);
  };

  f32x4 acc[8][3];
  const f32x4 z = {0.f, 0.f, 0.f, 0.f};
#pragma unroll
  for (int i = 0; i < 8; ++i)
#pragma unroll
    for (int j = 0; j < 3; ++j) acc[i][j] = z;

  QSTAGE_A(0, 0); QSTAGE_B(0, 0);
  QSTAGE_B(1, 1);
  asm volatile("s_waitcnt vmcnt(3)" ::: "memory");
  BARRIER();

  bf16x8 a[4][2], b[3][2];
  int cur = 0;
  for (int t = 0; t < nt; ++t, cur ^= 1) {
#pragma unroll
    for (int mi = 0; mi < 4; ++mi) { a[mi][0] = rdA(cur, mi, 0); a[mi][1] = rdA(cur, mi, 1); }
#pragma unroll
    for (int ni = 0; ni < 3; ++ni) { b[ni][0] = rdB(cur, ni, 0); b[ni][1] = rdB(cur, ni, 1); }
    if (t + 1 < nt) QSTAGE_A(cur ^ 1, t + 1);
    __builtin_amdgcn_s_setprio(1);
#pragma unroll
    for (int mi = 0; mi < 4; ++mi)
#pragma unroll
      for (int ni = 0; ni < 3; ++ni) {
        MFMA_ACC(acc[mi][ni], a[mi][0], b[ni][0]);
        MFMA_ACC(acc[mi][ni], a[mi][1], b[ni][1]);
      }
    __builtin_amdgcn_s_setprio(0);
    BARRIER();
#pragma unroll
    for (int mi = 0; mi < 4; ++mi) { a[mi][0] = rdA(cur, mi + 4, 0); a[mi][1] = rdA(cur, mi + 4, 1); }
    if (t + 2 < nt) QSTAGE_B(cur, t + 2);
    __builtin_amdgcn_s_setprio(1);
#pragma unroll
    for (int mi = 0; mi < 4; ++mi)
#pragma unroll
      for (int ni = 0; ni < 3; ++ni) {
        MFMA_ACC(acc[mi + 4][ni], a[mi][0], b[ni][0]);
        MFMA_ACC(acc[mi + 4][ni], a[mi][1], b[ni][1]);
      }
    __builtin_amdgcn_s_setprio(0);
    if (t + 1 < nt) {
      if (t + 2 < nt) {
        asm volatile("s_waitcnt vmcnt(3)" ::: "memory");
      } else {
        asm volatile("s_waitcnt vmcnt(0)" ::: "memory");
      }
    }
    BARRIER();
  }

#pragma unroll
  for (int ni = 0; ni < 3; ++ni) {
    int col = n0 + wc * 48 + ni * 16 + (lane & 15);
    float bv = bias[col];
#pragma unroll
    for (int mi = 0; mi < 8; ++mi) {
      int rbase = m0 + wr * 128 + mi * 16 + hig * 4;
#pragma unroll
      for (int r = 0; r < 4; ++r)
        Ch[(size_t)(rbase + r) * QKVN + col] = __float2bfloat16(acc[mi][ni][r] + bv);
    }
  }
#undef QSTAGE_A
#undef QSTAGE_B
}

// ---------------- Wo GEMM: 256x128 tile, full K, 256 blocks, 2-phase pipelined ----------------
__global__ __launch_bounds__(512, 2) void wogemm_kernel(
    const bf16* __restrict__ A,   // [SEQ][HID]
    const bf16* __restrict__ Bt,  // [HID][HID]
    float* __restrict__ C) {      // [SEQ][HID]
  __shared__ bf16 lds[2][3][128 * 64];  // [buf][A0,A1,B]
  const int blk = blockIdx.x;
  const int xcd = blk & 7, loc = blk >> 3;
  const int n0 = (xcd * 4 + (loc & 3)) * 128;
  const int m0 = (loc >> 2) * 256;
  const int tid = threadIdx.x;
  const int lane = tid & 63;
  const int w = tid >> 6;
  const int wr = w >> 1, wc = w & 1;
  const int nt = HID / 64;

#define WSTAGE(buf, slot, t)                                                    \
  {                                                                             \
    const bf16* _s = ((slot) == 2) ? Bt : A;                                    \
    int _g0 = ((slot) == 2) ? n0 : (m0 + (slot) * 128);                         \
    _Pragma("unroll")                                                           \
    for (int _it = 0; _it < 2; ++_it) {                                         \
      int _row = w * 16 + _it * 8 + (lane >> 3);                                \
      int _ch = (lane & 7) ^ (_row & 7);                                        \
      gl_lds16(_s + (size_t)(_g0 + _row) * HID + (size_t)(t) * 64 + _ch * 8,    \
               &lds[buf][slot][(w * 16 + _it * 8) * 64]);                       \
    }                                                                           \
  }

  auto rdA = [&](int cur, int mi, int ks) {
    int rr = (wr & 1) * 64 + mi * 16 + (lane & 15);
    int byt = rr * 128 + (((ks * 32 + (lane >> 4) * 8) * 2) ^ ((rr & 7) << 4));
    return *reinterpret_cast<const bf16x8*>(
        reinterpret_cast<const char*>(&lds[cur][wr >> 1][0]) + byt);
  };
  auto rdB = [&](int cur, int ni, int ks) {
    int rr = wc * 64 + ni * 16 + (lane & 15);
    int byt = rr * 128 + (((ks * 32 + (lane >> 4) * 8) * 2) ^ ((rr & 7) << 4));
    return *reinterpret_cast<const bf16x8*>(
        reinterpret_cast<const char*>(&lds[cur][2][0]) + byt);
  };

  f32x4 acc[4][4];
  const f32x4 z = {0.f, 0.f, 0.f, 0.f};
#pragma unroll
  for (int i = 0; i < 4; ++i)
#pragma unroll
    for (int j = 0; j < 4; ++j) acc[i][j] = z;

  WSTAGE(0, 0, 0); WSTAGE(0, 1, 0); WSTAGE(0, 2, 0);
  WSTAGE(1, 2, 1);
  asm volatile("s_waitcnt vmcnt(2)" ::: "memory");
  BARRIER();

  bf16x8 a[2][2], b[4][2];
  int cur = 0;
  for (int t = 0; t < nt; ++t, cur ^= 1) {
#pragma unroll
    for (int mi = 0; mi < 2; ++mi) { a[mi][0] = rdA(cur, mi, 0); a[mi][1] = rdA(cur, mi, 1); }
#pragma unroll
    for (int ni = 0; ni < 4; ++ni) { b[ni][0] = rdB(cur, ni, 0); b[ni][1] = rdB(cur, ni, 1); }
    if (t + 1 < nt) { WSTAGE(cur ^ 1, 0, t + 1); WSTAGE(cur ^ 1, 1, t + 1); }
    __builtin_amdgcn_s_setprio(1);
#pragma unroll
    for (int mi = 0; mi < 2; ++mi)
#pragma unroll
      for (int ni = 0; ni < 4; ++ni) {
        MFMA_ACC(acc[mi][ni], a[mi][0], b[ni][0]);
        MFMA_ACC(acc[mi][ni], a[mi][1], b[ni][1]);
      }
    __builtin_amdgcn_s_setprio(0);
    BARRIER();
#pragma unroll
    for (int mi = 0; mi < 2; ++mi) { a[mi][0] = rdA(cur, mi + 2, 0); a[mi][1] = rdA(cur, mi + 2, 1); }
    if (t + 2 < nt) WSTAGE(cur, 2, t + 2);
    __builtin_amdgcn_s_setprio(1);
#pragma unroll
    for (int mi = 0; mi < 2; ++mi)
#pragma unroll
      for (int ni = 0; ni < 4; ++ni) {
        MFMA_ACC(acc[mi + 2][ni], a[mi][0], b[ni][0]);
        MFMA_ACC(acc[mi + 2][ni], a[mi][1], b[ni][1]);
      }
    __builtin_amdgcn_s_setprio(0);
    if (t + 1 < nt) {
      if (t + 2 < nt) {
        asm volatile("s_waitcnt vmcnt(2)" ::: "memory");
      } else {
        asm volatile("s_waitcnt vmcnt(0)" ::: "memory");
      }
    }
    BARRIER();
  }

#pragma unroll
  for (int ni = 0; ni < 4; ++ni) {
    int col = n0 + wc * 64 + ni * 16 + (lane & 15);
#pragma unroll
    for (int mi = 0; mi < 4; ++mi) {
      int rbase = m0 + wr * 64 + mi * 16 + (lane >> 4) * 4;
#pragma unroll
      for (int r = 0; r < 4; ++r)
        C[(size_t)(rbase + r) * HID + col] = acc[mi][ni][r];
    }
  }
#undef WSTAGE
}

// ---------------- flash attention: paired q-tiles (qb=pr and qb=31-pr) ----------------
__global__ __launch_bounds__(256) void attn_kernel(
    const bf16* __restrict__ Q, const bf16* __restrict__ Kb,
    const bf16* __restrict__ Vt, bf16* __restrict__ AO) {
  __shared__ bf16 Ks[64 * 128];
  __shared__ bf16 Vs[128 * 64];
  __shared__ bf16 Ps[4][16 * 64];
  const int tid = threadIdx.x, lane = tid & 63, w = tid >> 6;
  const int b = blockIdx.x;
  const int H = b & 31;
  const int pr = b >> 5;
  const int kvh = H >> 2;
  const int hig = lane >> 4;
  const int q_loc = lane & 15;
  const f32x4 z = {0.f, 0.f, 0.f, 0.f};

#pragma unroll
  for (int pass = 0; pass < 2; ++pass) {
    const int qb = pass ? (31 - pr) : pr;
    const int qw = qb * 64 + w * 16;
    const int qa = qw + q_loc;

    bf16x8 aq[4];
#pragma unroll
    for (int kd = 0; kd < 4; ++kd) {
      int row = qw + q_loc;
      int d = kd * 32 + hig * 8;
      aq[kd] = *reinterpret_cast<const bf16x8*>(Q + (size_t)row * HID + H * HD + d);
    }

    float m_run = -1e30f, l_run = 0.0f;
    f32x4 o[8];
#pragma unroll
    for (int dt = 0; dt < 8; ++dt) o[dt] = z;

    for (int t = 0; t <= qb; ++t) {
      int kvbase = t * 64;
#pragma unroll
      for (int it = 0; it < 4; ++it) {
        int c = w * 4 + it;
        int row = c * 4 + (lane >> 4);
        int sb = ((lane & 15) * 16) ^ ((row & 7) << 4);
        gl_lds16(Kb + (size_t)(kvbase + row) * KVDIM + kvh * HD + (sb >> 1), &Ks[c * 512]);
      }
#pragma unroll
      for (int it = 0; it < 4; ++it) {
        int c = w * 4 + it;
        int row = c * 8 + (lane >> 3);
        int sb = ((lane & 7) * 16) ^ ((row & 7) << 4);
        gl_lds16(Vt + (size_t)(kvh * HD + row) * SEQ + kvbase + (sb >> 1), &Vs[c * 512]);
      }
      __syncthreads();

      f32x4 sf[4];
#pragma unroll
      for (int j = 0; j < 4; ++j) sf[j] = z;
#pragma unroll
      for (int j = 0; j < 4; ++j) {
#pragma unroll
        for (int kd = 0; kd < 4; ++kd) {
          int r = j * 16 + q_loc;
          int byt = r * 256 + (((kd * 32 + hig * 8) * 2) ^ ((r & 7) << 4));
          bf16x8 kfr = *reinterpret_cast<const bf16x8*>(reinterpret_cast<const char*>(Ks) + byt);
          sf[j] = __builtin_amdgcn_mfma_f32_16x16x32_bf16(kfr, aq[kd], sf[j], 0, 0, 0);
        }
      }

      float vals[4][4];
      bool diag = (t == qb);
#pragma unroll
      for (int j = 0; j < 4; ++j)
#pragma unroll
        for (int r = 0; r < 4; ++r) {
          float v = sf[j][r];
          if (diag) {
            int ka = kvbase + j * 16 + hig * 4 + r;
            if (ka > qa) v = -1e30f;
          }
          vals[j][r] = v;
        }

      float m01 = fmaxf(fmaxf(vals[0][0], vals[0][1]), fmaxf(vals[0][2], vals[0][3]));
      float m23 = fmaxf(fmaxf(vals[1][0], vals[1][1]), fmaxf(vals[1][2], vals[1][3]));
      float m45 = fmaxf(fmaxf(vals[2][0], vals[2][1]), fmaxf(vals[2][2], vals[2][3]));
      float m67 = fmaxf(fmaxf(vals[3][0], vals[3][1]), fmaxf(vals[3][2], vals[3][3]));
      float m = fmaxf(fmaxf(m01, m23), fmaxf(m45, m67));
      m = fmaxf(m, __shfl_xor(m, 16));
      m = fmaxf(m, __shfl_xor(m, 32));
      float m_old = m_run;
      float mn = fmaxf(m_old, m);
      m_run = mn;
      float alpha = __builtin_exp2f(m_old - mn);

      float p[4][4];
      float rs = 0.0f;
#pragma unroll
      for (int j = 0; j < 4; ++j)
#pragma unroll
        for (int r = 0; r < 4; ++r) {
          p[j][r] = __builtin_exp2f(vals[j][r] - mn);
          rs += p[j][r];
        }
      rs += __shfl_xor(rs, 16);
      rs += __shfl_xor(rs, 32);
      l_run = l_run * alpha + rs;

#pragma unroll
      for (int j = 0; j < 4; ++j) {
        bf16 tmp[4] = {__float2bfloat16(p[j][0]), __float2bfloat16(p[j][1]),
                       __float2bfloat16(p[j][2]), __float2bfloat16(p[j][3])};
        int coff = (j * 16 + hig * 4) * 2;
        int byt = q_loc * 128 + (coff ^ ((q_loc & 7) << 4));
        *reinterpret_cast<uint2*>(reinterpret_cast<char*>(&Ps[w][0]) + byt) =
            *reinterpret_cast<const uint2*>(tmp);
      }

      if (__any(mn > m_old)) {
#pragma unroll
        for (int r = 0; r < 4; ++r) {
          float alr = __shfl(alpha, hig * 4 + r);
#pragma unroll
          for (int dt = 0; dt < 8; ++dt) o[dt][r] *= alr;
        }
      }

      bf16x8 pa[2];
#pragma unroll
      for (int ks = 0; ks < 2; ++ks) {
        int byt = q_loc * 128 + (((ks * 32 + hig * 8) * 2) ^ ((q_loc & 7) << 4));
        pa[ks] = *reinterpret_cast<const bf16x8*>(reinterpret_cast<const char*>(&Ps[w][0]) + byt);
      }
#pragma unroll
      for (int dt = 0; dt < 8; ++dt)
#pragma unroll
        for (int ks = 0; ks < 2; ++ks) {
          int vrow = dt * 16 + q_loc;
          int byt = vrow * 128 + (((ks * 32 + hig * 8) * 2) ^ ((vrow & 7) << 4));
          bf16x8 vb = *reinterpret_cast<const bf16x8*>(reinterpret_cast<const char*>(Vs) + byt);
          o[dt] = __builtin_amdgcn_mfma_f32_16x16x32_bf16(pa[ks], vb, o[dt], 0, 0, 0);
        }
      __syncthreads();
    }

#pragma unroll
    for (int r = 0; r < 4; ++r) {
      float li = __shfl(l_run, hig * 4 + r);
      float linv = 1.0f / li;
#pragma unroll
      for (int dt = 0; dt < 8; ++dt) {
        int qrow = qw + hig * 4 + r;
        int d = dt * 16 + q_loc;
        AO[(size_t)qrow * HID + H * HD + d] = __float2bfloat16(o[dt][r] * linv);
      }
    }
  }
}

extern "C" void kernel_launch(void* const* d_in, const int* in_sizes, int n_in,
                              void* d_out, int out_size, void* d_ws, size_t ws_size,
                              hipStream_t stream) {
  const float* hidden = (const float*)d_in[0];
  const float* Wq = (const float*)d_in[2];
  const float* bq = (const float*)d_in[3];
  const float* Wk = (const float*)d_in[4];
  const float* bk = (const float*)d_in[5];
  const float* Wv = (const float*)d_in[6];
  const float* bv = (const float*)d_in[7];
  const float* Wo = (const float*)d_in[8];
  float* out = (float*)d_out;

  // workspace map (144 MiB used):
  char* ws = (char*)d_ws;
  bf16*  Wqkvt  = (bf16*)(ws + (size_t)0 * MiB);    // 48 MiB  [Q|K|V]^T bf16
  bf16*  Xb     = (bf16*)(ws + (size_t)48 * MiB);   // 16 MiB
  bf16*  Cqkvh  = (bf16*)(ws + (size_t)64 * MiB);   // 24 MiB  bf16 QKV out [64,88)
  bf16*  Wot    = (bf16*)(ws + (size_t)88 * MiB);   // 32 MiB  [88,120)
  bf16*  Qb     = (bf16*)(ws + (size_t)120 * MiB);  // 16 MiB
  bf16*  Kb     = (bf16*)(ws + (size_t)136 * MiB);  // 4 MiB
  bf16*  Vt     = (bf16*)(ws + (size_t)140 * MiB);  // 4 MiB (ends 144)
  // stream-ordered aliases:
  float* bqkv   = (float*)Qb;                       // consumed by QKV GEMM, then rope overwrites
  bf16*  AO     = Cqkvh;                            // [64,80): Cqkvh dead after postqkv

  transpose_all_kernel<<<18456, dim3(64, 4), 0, stream>>>(
      Wq, Wk, Wv, Wo, Wqkvt, Wot, hidden, Xb, bq, bk, bv, bqkv);

  // QKV GEMM: 256x192 tiles, full K, 256 blocks, bf16 out
  qkvgemm_kernel<<<256, 512, 0, stream>>>(Xb, Wqkvt, bqkv, Cqkvh);

  // fused rope-Q (pre-scaled) / rope-K / V-transpose
  postqkv_kernel<<<12288, 256, 0, stream>>>(Cqkvh, Qb, Kb, Vt);

  // paired-q-tile attention: 512 blocks, exactly 33 tile-iters each
  attn_kernel<<<512, 256, 0, stream>>>(Qb, Kb, Vt, AO);

  // Wo GEMM: 256x128 tiles, full K, 256 blocks, fp32 direct to out
  wogemm_kernel<<<256, 512, 0, stream>>>(AO, Wot, out);
}